// Round 9
// baseline (135.236 us; speedup 1.0000x reference)
//
#include <hip/hip_runtime.h>
#include <math.h>

#define FIN 128
#define H 64
#define FOUT 2
#define NEG_SLOPE 0.2f
#define EPS 1e-16f

#define BM 64
#define BK 32
#define SCAN_CHUNK 2048   // elements per scan_a block (256 thr * 8)

// K0: zero int buffer (custom — runtime fillBufferAligned costs 41 us/launch!)
__global__ void k_zero_int(int* __restrict__ a, int n){
  int i = blockIdx.x*blockDim.x + threadIdx.x;
  if(i < n) a[i] = 0;
}

// K1: [N,128] @ [128, 64|64] -> xl, xr.  LDS-tiled, 4x8 register micro-tile.
// BM=64 -> 782 blocks (~3/CU) so occupancy hides LDS/barrier latency.
__global__ __launch_bounds__(256) void k_gemm1(
    const float* __restrict__ x, const float* __restrict__ Wl,
    const float* __restrict__ Wr, float* __restrict__ xl,
    float* __restrict__ xr, int N){
  __shared__ float xsT[BK][BM+4];   // [kk][row] transposed, 8.7 KB
  __shared__ float ws[BK][128];     // [kk][col], col<64 Wl else Wr, 16 KB
  int tid = threadIdx.x;
  int rowbase = blockIdx.x*BM;
  int tc = tid & 15, tr = tid >> 4;    // tr in [0,16)
  int r0 = tr*4, c0 = tc*4;
  float acc[4][8];
  #pragma unroll
  for(int i=0;i<4;i++)
    #pragma unroll
    for(int j=0;j<8;j++) acc[i][j]=0.f;

  int lrow = tid >> 2;            // 0..63 (x stage row)
  int lk8  = (tid & 3) * 8;       // k-offset 0,8,16,24
  int wkk  = tid >> 3;            // 0..31 (W stage row)
  int wfq  = tid & 7;             // 0..7

  for(int k0=0; k0<FIN; k0+=BK){
    __syncthreads();
    // stage x tile (transposed)
    {
      int grow = rowbase + lrow;
      float4 v0 = make_float4(0,0,0,0), v1 = make_float4(0,0,0,0);
      if(grow < N){
        v0 = *(const float4*)(x + (size_t)grow*FIN + k0 + lk8);
        v1 = *(const float4*)(x + (size_t)grow*FIN + k0 + lk8 + 4);
      }
      xsT[lk8+0][lrow]=v0.x; xsT[lk8+1][lrow]=v0.y; xsT[lk8+2][lrow]=v0.z; xsT[lk8+3][lrow]=v0.w;
      xsT[lk8+4][lrow]=v1.x; xsT[lk8+5][lrow]=v1.y; xsT[lk8+6][lrow]=v1.z; xsT[lk8+7][lrow]=v1.w;
    }
    // stage W tile
    #pragma unroll
    for(int i=0;i<4;i++){
      int c4 = (wfq + i*8)*4;
      const float* srcp = (c4 < 64) ? (Wl + (size_t)(k0+wkk)*H + c4)
                                    : (Wr + (size_t)(k0+wkk)*H + (c4-64));
      *(float4*)(&ws[wkk][c4]) = *(const float4*)srcp;
    }
    __syncthreads();
    #pragma unroll
    for(int kk=0; kk<BK; kk++){
      float4 av = *(float4*)(&xsT[kk][r0]);
      float4 b0 = *(float4*)(&ws[kk][c0]);        // Wl cols
      float4 b1 = *(float4*)(&ws[kk][64+c0]);     // Wr cols
      float a[4] = {av.x,av.y,av.z,av.w};
      float b[8] = {b0.x,b0.y,b0.z,b0.w,b1.x,b1.y,b1.z,b1.w};
      #pragma unroll
      for(int i=0;i<4;i++)
        #pragma unroll
        for(int j=0;j<8;j++)
          acc[i][j] += a[i]*b[j];
    }
  }
  #pragma unroll
  for(int i=0;i<4;i++){
    int row = rowbase + r0 + i;
    if(row < N){
      *(float4*)(xl + (size_t)row*H + c0) = make_float4(acc[i][0],acc[i][1],acc[i][2],acc[i][3]);
      *(float4*)(xr + (size_t)row*H + c0) = make_float4(acc[i][4],acc[i][5],acc[i][6],acc[i][7]);
    }
  }
}

// K2: degree count + per-edge rank (uses the atomic's return value; coalesced rank write)
__global__ void k_degree(const int* __restrict__ ei, int E, int Etot,
                         int* __restrict__ deg, int* __restrict__ rank){
  int i0 = (blockIdx.x*blockDim.x + threadIdx.x)*4;
  if(i0 >= Etot) return;
  if(i0 + 4 <= E && (E & 3) == 0){
    int4 d4 = *(const int4*)(ei + E + i0);
    int r0 = atomicAdd(&deg[d4.x],1);
    int r1 = atomicAdd(&deg[d4.y],1);
    int r2 = atomicAdd(&deg[d4.z],1);
    int r3 = atomicAdd(&deg[d4.w],1);
    *(int4*)(rank + i0) = make_int4(r0,r1,r2,r3);
  } else if(i0 >= E && i0 + 4 <= Etot){
    int v = i0 - E;
    int r0 = atomicAdd(&deg[v+0],1);
    int r1 = atomicAdd(&deg[v+1],1);
    int r2 = atomicAdd(&deg[v+2],1);
    int r3 = atomicAdd(&deg[v+3],1);
    *(int4*)(rank + i0) = make_int4(r0,r1,r2,r3);
  } else {
    #pragma unroll
    for(int q=0;q<4;q++){
      int i = i0+q; if(i>=Etot) break;
      int dst = (i<E) ? ei[E+i] : (i-E);
      rank[i] = atomicAdd(&deg[dst],1);
    }
  }
}

// K3a: per-block scan of deg (2048 elems/block), local-exclusive into rowptr, block totals
__global__ __launch_bounds__(256) void k_scan_a(const int* __restrict__ deg, int n,
                                                int* __restrict__ rowptr,
                                                int* __restrict__ blocksum){
  __shared__ int wsum[4];
  int tid = threadIdx.x, lane = tid & 63, wid = tid >> 6;
  int idx = blockIdx.x*SCAN_CHUNK + tid*8;
  int v[8];
  if(idx + 8 <= n){
    int4 a = *(const int4*)(deg + idx);
    int4 b = *(const int4*)(deg + idx + 4);
    v[0]=a.x;v[1]=a.y;v[2]=a.z;v[3]=a.w;v[4]=b.x;v[5]=b.y;v[6]=b.z;v[7]=b.w;
  } else {
    #pragma unroll
    for(int i=0;i<8;i++) v[i] = (idx+i<n)? deg[idx+i] : 0;
  }
  int pre[8]; int st=0;
  #pragma unroll
  for(int i=0;i<8;i++){ pre[i]=st; st+=v[i]; }
  int incl = st;
  #pragma unroll
  for(int o=1;o<64;o<<=1){ int u=__shfl_up(incl,o); if(lane>=o) incl+=u; }
  if(lane==63) wsum[wid]=incl;
  __syncthreads();
  if(tid==0){ int accu=0; for(int i=0;i<4;i++){ int t=wsum[i]; wsum[i]=accu; accu+=t; } }
  __syncthreads();
  int toff = wsum[wid] + incl - st;
  if(idx + 8 <= n){
    int4 o0 = make_int4(toff+pre[0],toff+pre[1],toff+pre[2],toff+pre[3]);
    int4 o1 = make_int4(toff+pre[4],toff+pre[5],toff+pre[6],toff+pre[7]);
    *(int4*)(rowptr+idx)=o0; *(int4*)(rowptr+idx+4)=o1;
  } else {
    #pragma unroll
    for(int i=0;i<8;i++) if(idx+i<n) rowptr[idx+i]=toff+pre[i];
  }
  if(tid==255) blocksum[blockIdx.x] = toff + st;
}

// K3b: exclusive scan of block sums (nb <= 64), total -> rowptr[n]
__global__ void k_scan_b(int* __restrict__ blocksum, int nb, int* __restrict__ rowptr, int n){
  int lane = threadIdx.x & 63;
  int v = (lane<nb)? blocksum[lane] : 0;
  int incl = v;
  #pragma unroll
  for(int o=1;o<64;o<<=1){ int u=__shfl_up(incl,o); if(lane>=o) incl+=u; }
  if(lane<nb) blocksum[lane] = incl - v;
  if(lane==63) rowptr[n] = incl;
}

// K3c: add block offsets
__global__ void k_scan_c(int* __restrict__ rowptr, const int* __restrict__ blocksum, int n){
  int i = blockIdx.x*blockDim.x + threadIdx.x;
  if(i<n) rowptr[i] += blocksum[i >> 11];  // SCAN_CHUNK = 2048
}

// K4: CSR fill — no atomics; p = rowptr[dst] + rank[i]; 4-wide MLP
__global__ void k_fill(const int* __restrict__ ei, int E, int Etot,
                       const int* __restrict__ rowptr,
                       const int* __restrict__ rank, int* __restrict__ csr_src){
  int i0 = (blockIdx.x*blockDim.x + threadIdx.x)*4;
  if(i0 >= Etot) return;
  if(i0 + 4 <= E && (E & 3) == 0){
    int4 s4 = *(const int4*)(ei + i0);
    int4 d4 = *(const int4*)(ei + E + i0);
    int4 r4 = *(const int4*)(rank + i0);
    csr_src[rowptr[d4.x] + r4.x] = s4.x;
    csr_src[rowptr[d4.y] + r4.y] = s4.y;
    csr_src[rowptr[d4.z] + r4.z] = s4.z;
    csr_src[rowptr[d4.w] + r4.w] = s4.w;
  } else if(i0 >= E && i0 + 4 <= Etot){
    int4 r4 = *(const int4*)(rank + i0);
    int v = i0 - E;
    csr_src[rowptr[v+0] + r4.x] = v+0;
    csr_src[rowptr[v+1] + r4.y] = v+1;
    csr_src[rowptr[v+2] + r4.z] = v+2;
    csr_src[rowptr[v+3] + r4.w] = v+3;
  } else {
    #pragma unroll
    for(int q=0;q<4;q++){
      int i = i0+q; if(i>=Etot) break;
      int src, dst;
      if(i<E){ src = ei[i]; dst = ei[E+i]; } else { src = i-E; dst = i-E; }
      csr_src[rowptr[dst] + rank[i]] = src;
    }
  }
}

// K5: fused layer-1 (no-max softmax).  16-lane group per node, 4 nodes/wave.
// Chunk-of-8 edges: all 8 csr_src loads + 8 xl gathers issued before consumption
// (40 gathers in flight per wave).  Tail = clamped index + masked weight.
__global__ void k_node1f(const int* __restrict__ rowptr, const int* __restrict__ csr_src,
                         const float* __restrict__ xl, const float* __restrict__ xr,
                         const float* __restrict__ att, const float* __restrict__ b1,
                         const float* __restrict__ Wl2, const float* __restrict__ Wr2,
                         float* __restrict__ xl2, float* __restrict__ xr2, int N){
  int node = blockIdx.x*16 + (threadIdx.x>>4);
  int gl = threadIdx.x & 15;
  if(node >= N) return;
  int f4 = gl*4;
  float4 attv = *(const float4*)(att + f4);
  float4 xrv  = *(const float4*)(xr + (size_t)node*H + f4);
  int s = rowptr[node], t = rowptr[node+1];
  float d = 0.f;
  float ax=0.f, ay=0.f, az=0.f, aw=0.f;

  for(int k=s; k<t; k+=8){
    int tl = t - 1;
    int ks[8]; float4 xv[8]; float msk[8];
    #pragma unroll
    for(int j=0;j<8;j++){
      int kj = k + j;
      ks[j] = (kj < t) ? kj : tl;
      msk[j] = (kj < t) ? 1.f : 0.f;
    }
    int ss[8];
    #pragma unroll
    for(int j=0;j<8;j++) ss[j] = csr_src[ks[j]];
    #pragma unroll
    for(int j=0;j<8;j++) xv[j] = *(const float4*)(xl + (size_t)ss[j]*H + f4);
    #pragma unroll
    for(int j=0;j<8;j++){
      float h0 = xv[j].x + xrv.x, h1 = xv[j].y + xrv.y;
      float h2 = xv[j].z + xrv.z, h3 = xv[j].w + xrv.w;
      float l0 = (h0>0.f)? h0 : NEG_SLOPE*h0;
      float l1 = (h1>0.f)? h1 : NEG_SLOPE*h1;
      float l2 = (h2>0.f)? h2 : NEG_SLOPE*h2;
      float l3 = (h3>0.f)? h3 : NEG_SLOPE*h3;
      float e = l0*attv.x + l1*attv.y + l2*attv.z + l3*attv.w;
      #pragma unroll
      for(int o=1;o<16;o<<=1) e += __shfl_xor(e,o);
      float w = msk[j] * __expf(e);
      d  += w;
      ax += w*xv[j].x; ay += w*xv[j].y; az += w*xv[j].z; aw += w*xv[j].w;
    }
  }

  float inv = 1.f/(d + EPS);
  float4 bv = *(const float4*)(b1 + f4);
  float h0 = ax*inv + bv.x, h1 = ay*inv + bv.y;
  float h2 = az*inv + bv.z, h3 = aw*inv + bv.w;
  // 4 projections within the 16-lane group
  float p0 = h0*Wl2[(f4+0)*FOUT+0] + h1*Wl2[(f4+1)*FOUT+0] + h2*Wl2[(f4+2)*FOUT+0] + h3*Wl2[(f4+3)*FOUT+0];
  float p1 = h0*Wl2[(f4+0)*FOUT+1] + h1*Wl2[(f4+1)*FOUT+1] + h2*Wl2[(f4+2)*FOUT+1] + h3*Wl2[(f4+3)*FOUT+1];
  float p2 = h0*Wr2[(f4+0)*FOUT+0] + h1*Wr2[(f4+1)*FOUT+0] + h2*Wr2[(f4+2)*FOUT+0] + h3*Wr2[(f4+3)*FOUT+0];
  float p3 = h0*Wr2[(f4+0)*FOUT+1] + h1*Wr2[(f4+1)*FOUT+1] + h2*Wr2[(f4+2)*FOUT+1] + h3*Wr2[(f4+3)*FOUT+1];
  #pragma unroll
  for(int o=1;o<16;o<<=1){
    p0 += __shfl_xor(p0,o); p1 += __shfl_xor(p1,o);
    p2 += __shfl_xor(p2,o); p3 += __shfl_xor(p3,o);
  }
  if(gl==0){
    *(float2*)(xl2 + node*2) = make_float2(p0,p1);
    *(float2*)(xr2 + node*2) = make_float2(p2,p3);
  }
}

// K7: layer-2 full conv, single pass (no-max), 16-lane group per node, 4 nodes/wave
__global__ void k_node2(const int* __restrict__ rowptr, const int* __restrict__ csr_src,
                        const float* __restrict__ xl2, const float* __restrict__ xr2,
                        const float* __restrict__ att2, const float* __restrict__ b2,
                        float* __restrict__ out, int N){
  int node = blockIdx.x*16 + (threadIdx.x>>4);
  int gl = threadIdx.x & 15;
  if(node >= N) return;
  int s = rowptr[node], t = rowptr[node+1];
  float2 xrv = *(const float2*)(xr2 + node*2);
  float a0 = att2[0], a1 = att2[1];
  float den=0.f, n0=0.f, n1=0.f;
  for(int k=s+gl; k<t; k+=16){
    int src = csr_src[k];
    float2 xs = *(const float2*)(xl2 + src*2);
    float h0 = xs.x + xrv.x, h1 = xs.y + xrv.y;
    float l0 = (h0>0.f)? h0 : NEG_SLOPE*h0;
    float l1 = (h1>0.f)? h1 : NEG_SLOPE*h1;
    float ex = __expf(l0*a0 + l1*a1);
    den += ex; n0 += ex*xs.x; n1 += ex*xs.y;
  }
  #pragma unroll
  for(int o=1;o<16;o<<=1){
    den += __shfl_xor(den,o);
    n0  += __shfl_xor(n0,o);
    n1  += __shfl_xor(n1,o);
  }
  if(gl==0){
    float inv = 1.f/(den + EPS);
    out[node*2+0] = n0*inv + b2[0];
    out[node*2+1] = n1*inv + b2[1];
  }
}

extern "C" void kernel_launch(void* const* d_in, const int* in_sizes, int n_in,
                              void* d_out, int out_size, void* d_ws, size_t ws_size,
                              hipStream_t stream){
  const float* x    = (const float*)d_in[0];
  const int*   ei   = (const int*)d_in[1];
  const float* Wl1  = (const float*)d_in[2];
  const float* Wr1  = (const float*)d_in[3];
  const float* att1 = (const float*)d_in[4];
  const float* b1   = (const float*)d_in[5];
  const float* Wl2  = (const float*)d_in[6];
  const float* Wr2  = (const float*)d_in[7];
  const float* att2 = (const float*)d_in[8];
  const float* b2   = (const float*)d_in[9];
  int N = in_sizes[0]/FIN;
  int E = in_sizes[1]/2;
  int Etot = E + N;
  int nscan = (N + SCAN_CHUNK - 1) / SCAN_CHUNK;   // 25 for N=50000 (<=64 supported)
  int nquad = (Etot + 3) / 4;                       // 4-edge packages

  char* w = (char*)d_ws;
  size_t off = 0;
  auto alloc = [&](size_t bytes)->void*{
    void* p = w + off;
    off = (off + bytes + 255) & ~(size_t)255;
    return p;
  };
  float* xl1     = (float*)alloc((size_t)N*H*4);
  float* xr1     = (float*)alloc((size_t)N*H*4);
  int*   csr_src = (int*)  alloc((size_t)Etot*4);
  int*   rank    = (int*)  alloc((size_t)Etot*4);
  int*   deg     = (int*)  alloc((size_t)N*4);
  int*   rowptr  = (int*)  alloc((size_t)(N+1)*4);
  int*   blocksum= (int*)  alloc((size_t)64*4);
  float* xl2     = (float*)alloc((size_t)N*2*4);
  float* xr2     = (float*)alloc((size_t)N*2*4);

  k_zero_int<<<(N+511)/512,512,0,stream>>>(deg, N);
  k_gemm1<<<(N+BM-1)/BM, 256, 0, stream>>>(x, Wl1, Wr1, xl1, xr1, N);
  k_degree<<<(nquad+255)/256,256,0,stream>>>(ei, E, Etot, deg, rank);
  k_scan_a<<<nscan,256,0,stream>>>(deg, N, rowptr, blocksum);
  k_scan_b<<<1,64,0,stream>>>(blocksum, nscan, rowptr, N);
  k_scan_c<<<(N+255)/256,256,0,stream>>>(rowptr, blocksum, N);
  k_fill<<<(nquad+255)/256,256,0,stream>>>(ei, E, Etot, rowptr, rank, csr_src);
  k_node1f<<<(N+15)/16, 256, 0, stream>>>(rowptr, csr_src, xl1, xr1, att1, b1, Wl2, Wr2, xl2, xr2, N);
  k_node2<<<(N+15)/16, 256, 0, stream>>>(rowptr, csr_src, xl2, xr2, att2, b2, (float*)d_out, N);
}

// Round 10
// 130.484 us; speedup vs baseline: 1.0364x; 1.0364x over previous
//
#include <hip/hip_runtime.h>
#include <math.h>

#define FIN 128
#define H 64
#define FOUT 2
#define NEG_SLOPE 0.2f
#define EPS 1e-16f

#define BM 64
#define BK 32
#define SCAN_CHUNK 2048   // elements per scan_a block (256 thr * 8)

// K0: zero int buffer (custom; do NOT use hipMemsetAsync — runtime fill kernel is slow)
__global__ void k_zero_int(int* __restrict__ a, int n){
  int i = blockIdx.x*blockDim.x + threadIdx.x;
  if(i < n) a[i] = 0;
}

// Preamble: exclusive scan of blocksum[0..nscan) into LDS bs[] (nscan <= 64).
__device__ __forceinline__ void load_bs(const int* __restrict__ blocksum, int nscan,
                                        int* bs, int tid){
  if(tid < 64){
    int v = (tid < nscan)? blocksum[tid] : 0;
    int incl = v;
    #pragma unroll
    for(int o=1;o<64;o<<=1){ int u=__shfl_up(incl,o); if(tid>=o) incl+=u; }
    bs[tid] = incl - v;
  }
  __syncthreads();
}

// K1: fused [degree+rank] (blocks 0..GD-1) || [gemm1] (blocks GD..GD+GG-1).
// Independent work: degree is latency/atomic-bound, gemm is VALU-bound — overlap on CUs.
__global__ __launch_bounds__(256) void k_deg_gemm(
    const int* __restrict__ ei, int E, int Etot,
    int* __restrict__ deg, int* __restrict__ rank, int GD,
    const float* __restrict__ x, const float* __restrict__ Wl,
    const float* __restrict__ Wr, float* __restrict__ xl,
    float* __restrict__ xr, int N){
  __shared__ float xsT[BK][BM+4];   // gemm part only
  __shared__ float ws[BK][128];
  int tid = threadIdx.x;

  if((int)blockIdx.x < GD){
    // ---- degree + rank part ----
    int i0 = (blockIdx.x*256 + tid)*4;
    if(i0 >= Etot) return;
    if(i0 + 4 <= E && (E & 3) == 0){
      int4 d4 = *(const int4*)(ei + E + i0);
      int r0 = atomicAdd(&deg[d4.x],1);
      int r1 = atomicAdd(&deg[d4.y],1);
      int r2 = atomicAdd(&deg[d4.z],1);
      int r3 = atomicAdd(&deg[d4.w],1);
      *(int4*)(rank + i0) = make_int4(r0,r1,r2,r3);
    } else if(i0 >= E && i0 + 4 <= Etot){
      int v = i0 - E;
      int r0 = atomicAdd(&deg[v+0],1);
      int r1 = atomicAdd(&deg[v+1],1);
      int r2 = atomicAdd(&deg[v+2],1);
      int r3 = atomicAdd(&deg[v+3],1);
      *(int4*)(rank + i0) = make_int4(r0,r1,r2,r3);
    } else {
      #pragma unroll
      for(int q=0;q<4;q++){
        int i = i0+q; if(i>=Etot) break;
        int dst = (i<E) ? ei[E+i] : (i-E);
        rank[i] = atomicAdd(&deg[dst],1);
      }
    }
    return;
  }

  // ---- gemm part: [N,128] @ [128, 64|64] -> xl, xr.  4x8 register micro-tile ----
  int rowbase = (blockIdx.x - GD)*BM;
  int tc = tid & 15, tr = tid >> 4;
  int r0 = tr*4, c0 = tc*4;
  float acc[4][8];
  #pragma unroll
  for(int i=0;i<4;i++)
    #pragma unroll
    for(int j=0;j<8;j++) acc[i][j]=0.f;

  int lrow = tid >> 2;
  int lk8  = (tid & 3) * 8;
  int wkk  = tid >> 3;
  int wfq  = tid & 7;

  for(int k0=0; k0<FIN; k0+=BK){
    __syncthreads();
    {
      int grow = rowbase + lrow;
      float4 v0 = make_float4(0,0,0,0), v1 = make_float4(0,0,0,0);
      if(grow < N){
        v0 = *(const float4*)(x + (size_t)grow*FIN + k0 + lk8);
        v1 = *(const float4*)(x + (size_t)grow*FIN + k0 + lk8 + 4);
      }
      xsT[lk8+0][lrow]=v0.x; xsT[lk8+1][lrow]=v0.y; xsT[lk8+2][lrow]=v0.z; xsT[lk8+3][lrow]=v0.w;
      xsT[lk8+4][lrow]=v1.x; xsT[lk8+5][lrow]=v1.y; xsT[lk8+6][lrow]=v1.z; xsT[lk8+7][lrow]=v1.w;
    }
    #pragma unroll
    for(int i=0;i<4;i++){
      int c4 = (wfq + i*8)*4;
      const float* srcp = (c4 < 64) ? (Wl + (size_t)(k0+wkk)*H + c4)
                                    : (Wr + (size_t)(k0+wkk)*H + (c4-64));
      *(float4*)(&ws[wkk][c4]) = *(const float4*)srcp;
    }
    __syncthreads();
    #pragma unroll
    for(int kk=0; kk<BK; kk++){
      float4 av = *(float4*)(&xsT[kk][r0]);
      float4 b0 = *(float4*)(&ws[kk][c0]);
      float4 b1 = *(float4*)(&ws[kk][64+c0]);
      float a[4] = {av.x,av.y,av.z,av.w};
      float b[8] = {b0.x,b0.y,b0.z,b0.w,b1.x,b1.y,b1.z,b1.w};
      #pragma unroll
      for(int i=0;i<4;i++)
        #pragma unroll
        for(int j=0;j<8;j++)
          acc[i][j] += a[i]*b[j];
    }
  }
  #pragma unroll
  for(int i=0;i<4;i++){
    int row = rowbase + r0 + i;
    if(row < N){
      *(float4*)(xl + (size_t)row*H + c0) = make_float4(acc[i][0],acc[i][1],acc[i][2],acc[i][3]);
      *(float4*)(xr + (size_t)row*H + c0) = make_float4(acc[i][4],acc[i][5],acc[i][6],acc[i][7]);
    }
  }
}

// K2: per-block scan of deg (2048 elems/block), LOCAL-exclusive into rowptr + block totals.
// Last block also writes rowptr[n] = its local total (consumers add bs[n>>11]).
__global__ __launch_bounds__(256) void k_scan_a(const int* __restrict__ deg, int n,
                                                int* __restrict__ rowptr,
                                                int* __restrict__ blocksum){
  __shared__ int wsum[4];
  int tid = threadIdx.x, lane = tid & 63, wid = tid >> 6;
  int idx = blockIdx.x*SCAN_CHUNK + tid*8;
  int v[8];
  if(idx + 8 <= n){
    int4 a = *(const int4*)(deg + idx);
    int4 b = *(const int4*)(deg + idx + 4);
    v[0]=a.x;v[1]=a.y;v[2]=a.z;v[3]=a.w;v[4]=b.x;v[5]=b.y;v[6]=b.z;v[7]=b.w;
  } else {
    #pragma unroll
    for(int i=0;i<8;i++) v[i] = (idx+i<n)? deg[idx+i] : 0;
  }
  int pre[8]; int st=0;
  #pragma unroll
  for(int i=0;i<8;i++){ pre[i]=st; st+=v[i]; }
  int incl = st;
  #pragma unroll
  for(int o=1;o<64;o<<=1){ int u=__shfl_up(incl,o); if(lane>=o) incl+=u; }
  if(lane==63) wsum[wid]=incl;
  __syncthreads();
  if(tid==0){ int accu=0; for(int i=0;i<4;i++){ int t=wsum[i]; wsum[i]=accu; accu+=t; } }
  __syncthreads();
  int toff = wsum[wid] + incl - st;
  if(idx + 8 <= n){
    int4 o0 = make_int4(toff+pre[0],toff+pre[1],toff+pre[2],toff+pre[3]);
    int4 o1 = make_int4(toff+pre[4],toff+pre[5],toff+pre[6],toff+pre[7]);
    *(int4*)(rowptr+idx)=o0; *(int4*)(rowptr+idx+4)=o1;
  } else {
    #pragma unroll
    for(int i=0;i<8;i++) if(idx+i<n) rowptr[idx+i]=toff+pre[i];
  }
  if(tid==255){
    blocksum[blockIdx.x] = toff + st;
    if(blockIdx.x == gridDim.x-1) rowptr[n] = toff + st;  // local total of last chunk
  }
}

// K3: CSR fill — no atomics; p = rowptr_local[dst] + bs[dst>>11] + rank[i]
__global__ void k_fill(const int* __restrict__ ei, int E, int Etot,
                       const int* __restrict__ rowptr,
                       const int* __restrict__ blocksum, int nscan,
                       const int* __restrict__ rank, int* __restrict__ csr_src){
  __shared__ int bs[64];
  int tid = threadIdx.x;
  load_bs(blocksum, nscan, bs, tid);
  int i0 = (blockIdx.x*blockDim.x + tid)*4;
  if(i0 >= Etot) return;
  if(i0 + 4 <= E && (E & 3) == 0){
    int4 s4 = *(const int4*)(ei + i0);
    int4 d4 = *(const int4*)(ei + E + i0);
    int4 r4 = *(const int4*)(rank + i0);
    csr_src[rowptr[d4.x] + bs[d4.x>>11] + r4.x] = s4.x;
    csr_src[rowptr[d4.y] + bs[d4.y>>11] + r4.y] = s4.y;
    csr_src[rowptr[d4.z] + bs[d4.z>>11] + r4.z] = s4.z;
    csr_src[rowptr[d4.w] + bs[d4.w>>11] + r4.w] = s4.w;
  } else if(i0 >= E && i0 + 4 <= Etot){
    int4 r4 = *(const int4*)(rank + i0);
    int v = i0 - E;
    csr_src[rowptr[v+0] + bs[(v+0)>>11] + r4.x] = v+0;
    csr_src[rowptr[v+1] + bs[(v+1)>>11] + r4.y] = v+1;
    csr_src[rowptr[v+2] + bs[(v+2)>>11] + r4.z] = v+2;
    csr_src[rowptr[v+3] + bs[(v+3)>>11] + r4.w] = v+3;
  } else {
    #pragma unroll
    for(int q=0;q<4;q++){
      int i = i0+q; if(i>=Etot) break;
      int src, dst;
      if(i<E){ src = ei[i]; dst = ei[E+i]; } else { src = i-E; dst = i-E; }
      csr_src[rowptr[dst] + bs[dst>>11] + rank[i]] = src;
    }
  }
}

// K4: fused layer-1 (no-max softmax).  16-lane group per node, 4 nodes/wave.
// Chunk-of-8 edges: all 8 csr_src loads + 8 xl gathers issued before consumption.
__global__ void k_node1f(const int* __restrict__ rowptr, const int* __restrict__ blocksum,
                         int nscan, const int* __restrict__ csr_src,
                         const float* __restrict__ xl, const float* __restrict__ xr,
                         const float* __restrict__ att, const float* __restrict__ b1,
                         const float* __restrict__ Wl2, const float* __restrict__ Wr2,
                         float* __restrict__ xl2, float* __restrict__ xr2, int N){
  __shared__ int bs[64];
  int tid = threadIdx.x;
  load_bs(blocksum, nscan, bs, tid);
  int node = blockIdx.x*16 + (tid>>4);
  int gl = tid & 15;
  if(node >= N) return;
  int f4 = gl*4;
  float4 attv = *(const float4*)(att + f4);
  float4 xrv  = *(const float4*)(xr + (size_t)node*H + f4);
  int s = rowptr[node]   + bs[node>>11];
  int t = rowptr[node+1] + bs[(node+1)>>11];
  float d = 0.f;
  float ax=0.f, ay=0.f, az=0.f, aw=0.f;

  for(int k=s; k<t; k+=8){
    int tl = t - 1;
    int ks[8]; float4 xv[8]; float msk[8];
    #pragma unroll
    for(int j=0;j<8;j++){
      int kj = k + j;
      ks[j] = (kj < t) ? kj : tl;
      msk[j] = (kj < t) ? 1.f : 0.f;
    }
    int ss[8];
    #pragma unroll
    for(int j=0;j<8;j++) ss[j] = csr_src[ks[j]];
    #pragma unroll
    for(int j=0;j<8;j++) xv[j] = *(const float4*)(xl + (size_t)ss[j]*H + f4);
    #pragma unroll
    for(int j=0;j<8;j++){
      float h0 = xv[j].x + xrv.x, h1 = xv[j].y + xrv.y;
      float h2 = xv[j].z + xrv.z, h3 = xv[j].w + xrv.w;
      float l0 = (h0>0.f)? h0 : NEG_SLOPE*h0;
      float l1 = (h1>0.f)? h1 : NEG_SLOPE*h1;
      float l2 = (h2>0.f)? h2 : NEG_SLOPE*h2;
      float l3 = (h3>0.f)? h3 : NEG_SLOPE*h3;
      float e = l0*attv.x + l1*attv.y + l2*attv.z + l3*attv.w;
      #pragma unroll
      for(int o=1;o<16;o<<=1) e += __shfl_xor(e,o);
      float w = msk[j] * __expf(e);
      d  += w;
      ax += w*xv[j].x; ay += w*xv[j].y; az += w*xv[j].z; aw += w*xv[j].w;
    }
  }

  float inv = 1.f/(d + EPS);
  float4 bv = *(const float4*)(b1 + f4);
  float h0 = ax*inv + bv.x, h1 = ay*inv + bv.y;
  float h2 = az*inv + bv.z, h3 = aw*inv + bv.w;
  float p0 = h0*Wl2[(f4+0)*FOUT+0] + h1*Wl2[(f4+1)*FOUT+0] + h2*Wl2[(f4+2)*FOUT+0] + h3*Wl2[(f4+3)*FOUT+0];
  float p1 = h0*Wl2[(f4+0)*FOUT+1] + h1*Wl2[(f4+1)*FOUT+1] + h2*Wl2[(f4+2)*FOUT+1] + h3*Wl2[(f4+3)*FOUT+1];
  float p2 = h0*Wr2[(f4+0)*FOUT+0] + h1*Wr2[(f4+1)*FOUT+0] + h2*Wr2[(f4+2)*FOUT+0] + h3*Wr2[(f4+3)*FOUT+0];
  float p3 = h0*Wr2[(f4+0)*FOUT+1] + h1*Wr2[(f4+1)*FOUT+1] + h2*Wr2[(f4+2)*FOUT+1] + h3*Wr2[(f4+3)*FOUT+1];
  #pragma unroll
  for(int o=1;o<16;o<<=1){
    p0 += __shfl_xor(p0,o); p1 += __shfl_xor(p1,o);
    p2 += __shfl_xor(p2,o); p3 += __shfl_xor(p3,o);
  }
  if(gl==0){
    *(float2*)(xl2 + node*2) = make_float2(p0,p1);
    *(float2*)(xr2 + node*2) = make_float2(p2,p3);
  }
}

// K5: layer-2 full conv, single pass (no-max), 16-lane group per node, 4 nodes/wave
__global__ void k_node2(const int* __restrict__ rowptr, const int* __restrict__ blocksum,
                        int nscan, const int* __restrict__ csr_src,
                        const float* __restrict__ xl2, const float* __restrict__ xr2,
                        const float* __restrict__ att2, const float* __restrict__ b2,
                        float* __restrict__ out, int N){
  __shared__ int bs[64];
  int tid = threadIdx.x;
  load_bs(blocksum, nscan, bs, tid);
  int node = blockIdx.x*16 + (tid>>4);
  int gl = tid & 15;
  if(node >= N) return;
  int s = rowptr[node]   + bs[node>>11];
  int t = rowptr[node+1] + bs[(node+1)>>11];
  float2 xrv = *(const float2*)(xr2 + node*2);
  float a0 = att2[0], a1 = att2[1];
  float den=0.f, n0=0.f, n1=0.f;
  for(int k=s+gl; k<t; k+=16){
    int src = csr_src[k];
    float2 xs = *(const float2*)(xl2 + src*2);
    float h0 = xs.x + xrv.x, h1 = xs.y + xrv.y;
    float l0 = (h0>0.f)? h0 : NEG_SLOPE*h0;
    float l1 = (h1>0.f)? h1 : NEG_SLOPE*h1;
    float ex = __expf(l0*a0 + l1*a1);
    den += ex; n0 += ex*xs.x; n1 += ex*xs.y;
  }
  #pragma unroll
  for(int o=1;o<16;o<<=1){
    den += __shfl_xor(den,o);
    n0  += __shfl_xor(n0,o);
    n1  += __shfl_xor(n1,o);
  }
  if(gl==0){
    float inv = 1.f/(den + EPS);
    out[node*2+0] = n0*inv + b2[0];
    out[node*2+1] = n1*inv + b2[1];
  }
}

extern "C" void kernel_launch(void* const* d_in, const int* in_sizes, int n_in,
                              void* d_out, int out_size, void* d_ws, size_t ws_size,
                              hipStream_t stream){
  const float* x    = (const float*)d_in[0];
  const int*   ei   = (const int*)d_in[1];
  const float* Wl1  = (const float*)d_in[2];
  const float* Wr1  = (const float*)d_in[3];
  const float* att1 = (const float*)d_in[4];
  const float* b1   = (const float*)d_in[5];
  const float* Wl2  = (const float*)d_in[6];
  const float* Wr2  = (const float*)d_in[7];
  const float* att2 = (const float*)d_in[8];
  const float* b2   = (const float*)d_in[9];
  int N = in_sizes[0]/FIN;
  int E = in_sizes[1]/2;
  int Etot = E + N;
  int nscan = (N + SCAN_CHUNK - 1) / SCAN_CHUNK;   // 25 for N=50000 (<=64 required)
  int nquad = (Etot + 3) / 4;
  int GD = (nquad + 255) / 256;                    // degree-part blocks
  int GG = (N + BM - 1) / BM;                      // gemm-part blocks

  char* w = (char*)d_ws;
  size_t off = 0;
  auto alloc = [&](size_t bytes)->void*{
    void* p = w + off;
    off = (off + bytes + 255) & ~(size_t)255;
    return p;
  };
  float* xl1     = (float*)alloc((size_t)N*H*4);
  float* xr1     = (float*)alloc((size_t)N*H*4);
  int*   csr_src = (int*)  alloc((size_t)Etot*4);
  int*   rank    = (int*)  alloc((size_t)Etot*4);
  int*   deg     = (int*)  alloc((size_t)N*4);
  int*   rowptr  = (int*)  alloc((size_t)(N+1)*4);
  int*   blocksum= (int*)  alloc((size_t)64*4);
  float* xl2     = (float*)alloc((size_t)N*2*4);
  float* xr2     = (float*)alloc((size_t)N*2*4);

  k_zero_int<<<(N+511)/512,512,0,stream>>>(deg, N);
  k_deg_gemm<<<GD+GG, 256, 0, stream>>>(ei, E, Etot, deg, rank, GD,
                                        x, Wl1, Wr1, xl1, xr1, N);
  k_scan_a<<<nscan,256,0,stream>>>(deg, N, rowptr, blocksum);
  k_fill<<<GD,256,0,stream>>>(ei, E, Etot, rowptr, blocksum, nscan, rank, csr_src);
  k_node1f<<<(N+15)/16, 256, 0, stream>>>(rowptr, blocksum, nscan, csr_src,
                                          xl1, xr1, att1, b1, Wl2, Wr2, xl2, xr2, N);
  k_node2<<<(N+15)/16, 256, 0, stream>>>(rowptr, blocksum, nscan, csr_src,
                                         xl2, xr2, att2, b2, (float*)d_out, N);
}

// Round 11
// 128.849 us; speedup vs baseline: 1.0496x; 1.0127x over previous
//
#include <hip/hip_runtime.h>
#include <math.h>

#define FIN 128
#define H 64
#define FOUT 2
#define NEG_SLOPE 0.2f
#define EPS 1e-16f

#define SCAN_CHUNK 2048   // elements per scan_a block (256 thr * 8)

typedef __attribute__((ext_vector_type(8))) short s8v;   // 8 bf16 (4 VGPR)
typedef __attribute__((ext_vector_type(4))) float f4v;   // MFMA acc

// Preamble: exclusive scan of blocksum[0..nscan) into LDS bs[] (nscan <= 64).
__device__ __forceinline__ void load_bs(const int* __restrict__ blocksum, int nscan,
                                        int* bs, int tid){
  if(tid < 64){
    int v = (tid < nscan)? blocksum[tid] : 0;
    int incl = v;
    #pragma unroll
    for(int o=1;o<64;o<<=1){ int u=__shfl_up(incl,o); if(tid>=o) incl+=u; }
    bs[tid] = incl - v;
  }
  __syncthreads();
}

// K0: fused [zero deg] + [pack W into MFMA B-fragments, split hi/lo bf16].
// Pack layout: pW[((ct*4+k0)*64 + lane)*8 + j] = W_all[k0*32 + (lane>>4)*8 + j][ct*16 + (lane&15)]
// where W_all = [Wl | Wr] (128 cols).  Any consistent k-bijection is valid since
// A and B fragments share the same (group,j)->k map.
__global__ void k_prep(int* __restrict__ deg, int N, int ZB,
                       const float* __restrict__ Wl, const float* __restrict__ Wr,
                       unsigned short* __restrict__ pWh, unsigned short* __restrict__ pWe){
  int b = blockIdx.x;
  if(b < ZB){
    int i = b*256 + threadIdx.x;
    if(i < N) deg[i] = 0;
    return;
  }
  int idx = (b - ZB)*256 + threadIdx.x;     // (ct*4+k0)*64 + lane, < 2048
  int lane = idx & 63;
  int ctk  = idx >> 6;                      // ct*4 + k0
  int k0   = (ctk & 3) * 32;
  int ct   = ctk >> 2;
  int c    = ct*16 + (lane & 15);
  int kb   = k0 + (lane >> 4)*8;
  const float* Wp = (c < 64) ? (Wl + c) : (Wr + (c - 64));
  #pragma unroll
  for(int j=0;j<8;j++){
    float v = Wp[(size_t)(kb + j)*H];
    unsigned u = __float_as_uint(v);
    unsigned short hb = (unsigned short)(u >> 16);
    float hv = __uint_as_float(((unsigned)hb) << 16);
    float ev = v - hv;
    unsigned short eb = (unsigned short)(__float_as_uint(ev) >> 16);
    pWh[(size_t)idx*8 + j] = hb;
    pWe[(size_t)idx*8 + j] = eb;
  }
}

// K1: MFMA GEMM  [N,128] @ [128, 64|64] -> xl, xr  via bf16x3 split.
// Wave = 16 rows x 128 cols (8 col-tiles of 16x16x32), 4 k-steps, 96 MFMA/wave.
// No LDS, no barriers.  C/D map (HW-verified): col=lane&15, row=(lane>>4)*4+reg.
__global__ __launch_bounds__(256) void k_gemm_mfma(
    const float* __restrict__ x,
    const unsigned short* __restrict__ pWh, const unsigned short* __restrict__ pWe,
    float* __restrict__ xl, float* __restrict__ xr, int N){
  int tid = threadIdx.x;
  int lane = tid & 63, wid = tid >> 6;
  int rowbase = blockIdx.x*64 + wid*16;
  int r = lane & 15, g = lane >> 4;
  f4v acc[8];
  #pragma unroll
  for(int ct=0;ct<8;ct++) acc[ct] = (f4v){0.f,0.f,0.f,0.f};

  int arow = rowbase + r; if(arow > N-1) arow = N-1;   // clamp; bad rows never stored
  const float* xrow = x + (size_t)arow*FIN;

  #pragma unroll
  for(int k0=0;k0<4;k0++){
    float4 va = *(const float4*)(xrow + k0*32 + g*8);
    float4 vb = *(const float4*)(xrow + k0*32 + g*8 + 4);
    float xs_[8] = {va.x,va.y,va.z,va.w,vb.x,vb.y,vb.z,vb.w};
    s8v ah, ae;
    #pragma unroll
    for(int j=0;j<8;j++){
      unsigned u = __float_as_uint(xs_[j]);
      unsigned short hb = (unsigned short)(u >> 16);
      ah[j] = (short)hb;
      float ev = xs_[j] - __uint_as_float(((unsigned)hb) << 16);
      ae[j] = (short)(unsigned short)(__float_as_uint(ev) >> 16);
    }
    #pragma unroll
    for(int ct=0;ct<8;ct++){
      size_t boff = ((size_t)(ct*4 + k0)*64 + lane)*8;
      s8v bh = *(const s8v*)(pWh + boff);
      s8v be = *(const s8v*)(pWe + boff);
      acc[ct] = __builtin_amdgcn_mfma_f32_16x16x32_bf16(ah, bh, acc[ct], 0,0,0);
      acc[ct] = __builtin_amdgcn_mfma_f32_16x16x32_bf16(ah, be, acc[ct], 0,0,0);
      acc[ct] = __builtin_amdgcn_mfma_f32_16x16x32_bf16(ae, bh, acc[ct], 0,0,0);
    }
  }
  #pragma unroll
  for(int ct=0;ct<8;ct++){
    float* dst = (ct < 4) ? xl : xr;
    int cc = (ct & 3)*16 + r;
    #pragma unroll
    for(int rr=0;rr<4;rr++){
      int row = rowbase + g*4 + rr;
      if(row < N) dst[(size_t)row*H + cc] = acc[ct][rr];
    }
  }
}

// K2: degree count + per-edge rank (standalone — fusion with gemm measured slower)
__global__ void k_degree(const int* __restrict__ ei, int E, int Etot,
                         int* __restrict__ deg, int* __restrict__ rank){
  int i0 = (blockIdx.x*blockDim.x + threadIdx.x)*4;
  if(i0 >= Etot) return;
  if(i0 + 4 <= E && (E & 3) == 0){
    int4 d4 = *(const int4*)(ei + E + i0);
    int r0 = atomicAdd(&deg[d4.x],1);
    int r1 = atomicAdd(&deg[d4.y],1);
    int r2 = atomicAdd(&deg[d4.z],1);
    int r3 = atomicAdd(&deg[d4.w],1);
    *(int4*)(rank + i0) = make_int4(r0,r1,r2,r3);
  } else if(i0 >= E && i0 + 4 <= Etot){
    int v = i0 - E;
    int r0 = atomicAdd(&deg[v+0],1);
    int r1 = atomicAdd(&deg[v+1],1);
    int r2 = atomicAdd(&deg[v+2],1);
    int r3 = atomicAdd(&deg[v+3],1);
    *(int4*)(rank + i0) = make_int4(r0,r1,r2,r3);
  } else {
    #pragma unroll
    for(int q=0;q<4;q++){
      int i = i0+q; if(i>=Etot) break;
      int dst = (i<E) ? ei[E+i] : (i-E);
      rank[i] = atomicAdd(&deg[dst],1);
    }
  }
}

// K3: per-block scan of deg (2048/block), LOCAL-exclusive into rowptr + block totals.
// Last block also writes rowptr[n] = its local total (consumers add bs[n>>11]).
__global__ __launch_bounds__(256) void k_scan_a(const int* __restrict__ deg, int n,
                                                int* __restrict__ rowptr,
                                                int* __restrict__ blocksum){
  __shared__ int wsum[4];
  int tid = threadIdx.x, lane = tid & 63, wid = tid >> 6;
  int idx = blockIdx.x*SCAN_CHUNK + tid*8;
  int v[8];
  if(idx + 8 <= n){
    int4 a = *(const int4*)(deg + idx);
    int4 b = *(const int4*)(deg + idx + 4);
    v[0]=a.x;v[1]=a.y;v[2]=a.z;v[3]=a.w;v[4]=b.x;v[5]=b.y;v[6]=b.z;v[7]=b.w;
  } else {
    #pragma unroll
    for(int i=0;i<8;i++) v[i] = (idx+i<n)? deg[idx+i] : 0;
  }
  int pre[8]; int st=0;
  #pragma unroll
  for(int i=0;i<8;i++){ pre[i]=st; st+=v[i]; }
  int incl = st;
  #pragma unroll
  for(int o=1;o<64;o<<=1){ int u=__shfl_up(incl,o); if(lane>=o) incl+=u; }
  if(lane==63) wsum[wid]=incl;
  __syncthreads();
  if(tid==0){ int accu=0; for(int i=0;i<4;i++){ int t=wsum[i]; wsum[i]=accu; accu+=t; } }
  __syncthreads();
  int toff = wsum[wid] + incl - st;
  if(idx + 8 <= n){
    int4 o0 = make_int4(toff+pre[0],toff+pre[1],toff+pre[2],toff+pre[3]);
    int4 o1 = make_int4(toff+pre[4],toff+pre[5],toff+pre[6],toff+pre[7]);
    *(int4*)(rowptr+idx)=o0; *(int4*)(rowptr+idx+4)=o1;
  } else {
    #pragma unroll
    for(int i=0;i<8;i++) if(idx+i<n) rowptr[idx+i]=toff+pre[i];
  }
  if(tid==255){
    blocksum[blockIdx.x] = toff + st;
    if(blockIdx.x == gridDim.x-1) rowptr[n] = toff + st;
  }
}

// K4: CSR fill — no atomics; p = rowptr_local[dst] + bs[dst>>11] + rank[i]
__global__ void k_fill(const int* __restrict__ ei, int E, int Etot,
                       const int* __restrict__ rowptr,
                       const int* __restrict__ blocksum, int nscan,
                       const int* __restrict__ rank, int* __restrict__ csr_src){
  __shared__ int bs[64];
  int tid = threadIdx.x;
  load_bs(blocksum, nscan, bs, tid);
  int i0 = (blockIdx.x*blockDim.x + tid)*4;
  if(i0 >= Etot) return;
  if(i0 + 4 <= E && (E & 3) == 0){
    int4 s4 = *(const int4*)(ei + i0);
    int4 d4 = *(const int4*)(ei + E + i0);
    int4 r4 = *(const int4*)(rank + i0);
    csr_src[rowptr[d4.x] + bs[d4.x>>11] + r4.x] = s4.x;
    csr_src[rowptr[d4.y] + bs[d4.y>>11] + r4.y] = s4.y;
    csr_src[rowptr[d4.z] + bs[d4.z>>11] + r4.z] = s4.z;
    csr_src[rowptr[d4.w] + bs[d4.w>>11] + r4.w] = s4.w;
  } else if(i0 >= E && i0 + 4 <= Etot){
    int4 r4 = *(const int4*)(rank + i0);
    int v = i0 - E;
    csr_src[rowptr[v+0] + bs[(v+0)>>11] + r4.x] = v+0;
    csr_src[rowptr[v+1] + bs[(v+1)>>11] + r4.y] = v+1;
    csr_src[rowptr[v+2] + bs[(v+2)>>11] + r4.z] = v+2;
    csr_src[rowptr[v+3] + bs[(v+3)>>11] + r4.w] = v+3;
  } else {
    #pragma unroll
    for(int q=0;q<4;q++){
      int i = i0+q; if(i>=Etot) break;
      int src, dst;
      if(i<E){ src = ei[i]; dst = ei[E+i]; } else { src = i-E; dst = i-E; }
      csr_src[rowptr[dst] + bs[dst>>11] + rank[i]] = src;
    }
  }
}

// K5: fused layer-1 (no-max softmax).  16-lane group per node, 4 nodes/wave.
// Chunk-of-8 edges: all 8 csr_src loads + 8 xl gathers issued before consumption.
__global__ void k_node1f(const int* __restrict__ rowptr, const int* __restrict__ blocksum,
                         int nscan, const int* __restrict__ csr_src,
                         const float* __restrict__ xl, const float* __restrict__ xr,
                         const float* __restrict__ att, const float* __restrict__ b1,
                         const float* __restrict__ Wl2, const float* __restrict__ Wr2,
                         float* __restrict__ xl2, float* __restrict__ xr2, int N){
  __shared__ int bs[64];
  int tid = threadIdx.x;
  load_bs(blocksum, nscan, bs, tid);
  int node = blockIdx.x*16 + (tid>>4);
  int gl = tid & 15;
  if(node >= N) return;
  int f4 = gl*4;
  float4 attv = *(const float4*)(att + f4);
  float4 xrv  = *(const float4*)(xr + (size_t)node*H + f4);
  int s = rowptr[node]   + bs[node>>11];
  int t = rowptr[node+1] + bs[(node+1)>>11];
  float d = 0.f;
  float ax=0.f, ay=0.f, az=0.f, aw=0.f;

  for(int k=s; k<t; k+=8){
    int tl = t - 1;
    int ks[8]; float4 xv[8]; float msk[8];
    #pragma unroll
    for(int j=0;j<8;j++){
      int kj = k + j;
      ks[j] = (kj < t) ? kj : tl;
      msk[j] = (kj < t) ? 1.f : 0.f;
    }
    int ss[8];
    #pragma unroll
    for(int j=0;j<8;j++) ss[j] = csr_src[ks[j]];
    #pragma unroll
    for(int j=0;j<8;j++) xv[j] = *(const float4*)(xl + (size_t)ss[j]*H + f4);
    #pragma unroll
    for(int j=0;j<8;j++){
      float h0 = xv[j].x + xrv.x, h1 = xv[j].y + xrv.y;
      float h2 = xv[j].z + xrv.z, h3 = xv[j].w + xrv.w;
      float l0 = (h0>0.f)? h0 : NEG_SLOPE*h0;
      float l1 = (h1>0.f)? h1 : NEG_SLOPE*h1;
      float l2 = (h2>0.f)? h2 : NEG_SLOPE*h2;
      float l3 = (h3>0.f)? h3 : NEG_SLOPE*h3;
      float e = l0*attv.x + l1*attv.y + l2*attv.z + l3*attv.w;
      #pragma unroll
      for(int o=1;o<16;o<<=1) e += __shfl_xor(e,o);
      float w = msk[j] * __expf(e);
      d  += w;
      ax += w*xv[j].x; ay += w*xv[j].y; az += w*xv[j].z; aw += w*xv[j].w;
    }
  }

  float inv = 1.f/(d + EPS);
  float4 bv = *(const float4*)(b1 + f4);
  float h0 = ax*inv + bv.x, h1 = ay*inv + bv.y;
  float h2 = az*inv + bv.z, h3 = aw*inv + bv.w;
  float p0 = h0*Wl2[(f4+0)*FOUT+0] + h1*Wl2[(f4+1)*FOUT+0] + h2*Wl2[(f4+2)*FOUT+0] + h3*Wl2[(f4+3)*FOUT+0];
  float p1 = h0*Wl2[(f4+0)*FOUT+1] + h1*Wl2[(f4+1)*FOUT+1] + h2*Wl2[(f4+2)*FOUT+1] + h3*Wl2[(f4+3)*FOUT+1];
  float p2 = h0*Wr2[(f4+0)*FOUT+0] + h1*Wr2[(f4+1)*FOUT+0] + h2*Wr2[(f4+2)*FOUT+0] + h3*Wr2[(f4+3)*FOUT+0];
  float p3 = h0*Wr2[(f4+0)*FOUT+1] + h1*Wr2[(f4+1)*FOUT+1] + h2*Wr2[(f4+2)*FOUT+1] + h3*Wr2[(f4+3)*FOUT+1];
  #pragma unroll
  for(int o=1;o<16;o<<=1){
    p0 += __shfl_xor(p0,o); p1 += __shfl_xor(p1,o);
    p2 += __shfl_xor(p2,o); p3 += __shfl_xor(p3,o);
  }
  if(gl==0){
    *(float2*)(xl2 + node*2) = make_float2(p0,p1);
    *(float2*)(xr2 + node*2) = make_float2(p2,p3);
  }
}

// K6: layer-2 full conv, single pass (no-max), 16-lane group per node, 4 nodes/wave
__global__ void k_node2(const int* __restrict__ rowptr, const int* __restrict__ blocksum,
                        int nscan, const int* __restrict__ csr_src,
                        const float* __restrict__ xl2, const float* __restrict__ xr2,
                        const float* __restrict__ att2, const float* __restrict__ b2,
                        float* __restrict__ out, int N){
  __shared__ int bs[64];
  int tid = threadIdx.x;
  load_bs(blocksum, nscan, bs, tid);
  int node = blockIdx.x*16 + (tid>>4);
  int gl = tid & 15;
  if(node >= N) return;
  int s = rowptr[node]   + bs[node>>11];
  int t = rowptr[node+1] + bs[(node+1)>>11];
  float2 xrv = *(const float2*)(xr2 + node*2);
  float a0 = att2[0], a1 = att2[1];
  float den=0.f, n0=0.f, n1=0.f;
  for(int k=s+gl; k<t; k+=16){
    int src = csr_src[k];
    float2 xs = *(const float2*)(xl2 + src*2);
    float h0 = xs.x + xrv.x, h1 = xs.y + xrv.y;
    float l0 = (h0>0.f)? h0 : NEG_SLOPE*h0;
    float l1 = (h1>0.f)? h1 : NEG_SLOPE*h1;
    float ex = __expf(l0*a0 + l1*a1);
    den += ex; n0 += ex*xs.x; n1 += ex*xs.y;
  }
  #pragma unroll
  for(int o=1;o<16;o<<=1){
    den += __shfl_xor(den,o);
    n0  += __shfl_xor(n0,o);
    n1  += __shfl_xor(n1,o);
  }
  if(gl==0){
    float inv = 1.f/(den + EPS);
    out[node*2+0] = n0*inv + b2[0];
    out[node*2+1] = n1*inv + b2[1];
  }
}

extern "C" void kernel_launch(void* const* d_in, const int* in_sizes, int n_in,
                              void* d_out, int out_size, void* d_ws, size_t ws_size,
                              hipStream_t stream){
  const float* x    = (const float*)d_in[0];
  const int*   ei   = (const int*)d_in[1];
  const float* Wl1  = (const float*)d_in[2];
  const float* Wr1  = (const float*)d_in[3];
  const float* att1 = (const float*)d_in[4];
  const float* b1   = (const float*)d_in[5];
  const float* Wl2  = (const float*)d_in[6];
  const float* Wr2  = (const float*)d_in[7];
  const float* att2 = (const float*)d_in[8];
  const float* b2   = (const float*)d_in[9];
  int N = in_sizes[0]/FIN;
  int E = in_sizes[1]/2;
  int Etot = E + N;
  int nscan = (N + SCAN_CHUNK - 1) / SCAN_CHUNK;   // 25 for N=50000 (<=64 required)
  int nquad = (Etot + 3) / 4;
  int ZB = (N + 255) / 256;                        // zero-part blocks in k_prep

  char* w = (char*)d_ws;
  size_t off = 0;
  auto alloc = [&](size_t bytes)->void*{
    void* p = w + off;
    off = (off + bytes + 255) & ~(size_t)255;
    return p;
  };
  float* xl1     = (float*)alloc((size_t)N*H*4);
  float* xr1     = (float*)alloc((size_t)N*H*4);
  int*   csr_src = (int*)  alloc((size_t)Etot*4);
  int*   rank    = (int*)  alloc((size_t)Etot*4);
  int*   deg     = (int*)  alloc((size_t)N*4);
  int*   rowptr  = (int*)  alloc((size_t)(N+1)*4);
  int*   blocksum= (int*)  alloc((size_t)64*4);
  float* xl2     = (float*)alloc((size_t)N*2*4);
  float* xr2     = (float*)alloc((size_t)N*2*4);
  unsigned short* pWh = (unsigned short*)alloc((size_t)2048*8*2);
  unsigned short* pWe = (unsigned short*)alloc((size_t)2048*8*2);

  k_prep<<<ZB+8, 256, 0, stream>>>(deg, N, ZB, Wl1, Wr1, pWh, pWe);
  k_gemm_mfma<<<(N+63)/64, 256, 0, stream>>>(x, pWh, pWe, xl1, xr1, N);
  k_degree<<<(nquad+255)/256,256,0,stream>>>(ei, E, Etot, deg, rank);
  k_scan_a<<<nscan,256,0,stream>>>(deg, N, rowptr, blocksum);
  k_fill<<<(nquad+255)/256,256,0,stream>>>(ei, E, Etot, rowptr, blocksum, nscan, rank, csr_src);
  k_node1f<<<(N+15)/16, 256, 0, stream>>>(rowptr, blocksum, nscan, csr_src,
                                          xl1, xr1, att1, b1, Wl2, Wr2, xl2, xr2, N);
  k_node2<<<(N+15)/16, 256, 0, stream>>>(rowptr, blocksum, nscan, csr_src,
                                         xl2, xr2, att2, b2, (float*)d_out, N);
}

// Round 12
// 125.864 us; speedup vs baseline: 1.0745x; 1.0237x over previous
//
#include <hip/hip_runtime.h>
#include <math.h>

#define FIN 128
#define H 64
#define FOUT 2
#define NEG_SLOPE 0.2f
#define EPS 1e-16f

#define SCAN_CHUNK 2048   // elements per scan_a block (256 thr * 8)

typedef __attribute__((ext_vector_type(8))) short s8v;   // 8 bf16 (4 VGPR)
typedef __attribute__((ext_vector_type(4))) float f4v;   // MFMA acc

// Preamble: exclusive scan of blocksum[0..nscan) into LDS bs[] (nscan <= 64).
__device__ __forceinline__ void load_bs(const int* __restrict__ blocksum, int nscan,
                                        int* bs, int tid){
  if(tid < 64){
    int v = (tid < nscan)? blocksum[tid] : 0;
    int incl = v;
    #pragma unroll
    for(int o=1;o<64;o<<=1){ int u=__shfl_up(incl,o); if(tid>=o) incl+=u; }
    bs[tid] = incl - v;
  }
  __syncthreads();
}

// K0: fused [zero deg] + [pack W into MFMA B-fragments, split hi/lo bf16].
// Pack layout: pW[((ct*4+k0)*64 + lane)*8 + j] = W_all[k0*32 + (lane>>4)*8 + j][ct*16 + (lane&15)]
// where W_all = [Wl | Wr] (128 cols).
__global__ void k_prep(int* __restrict__ deg, int N, int ZB,
                       const float* __restrict__ Wl, const float* __restrict__ Wr,
                       unsigned short* __restrict__ pWh, unsigned short* __restrict__ pWe){
  int b = blockIdx.x;
  if(b < ZB){
    int i = b*256 + threadIdx.x;
    if(i < N) deg[i] = 0;
    return;
  }
  int idx = (b - ZB)*256 + threadIdx.x;     // (ct*4+k0)*64 + lane, < 2048
  int lane = idx & 63;
  int ctk  = idx >> 6;                      // ct*4 + k0
  int k0   = (ctk & 3) * 32;
  int ct   = ctk >> 2;
  int c    = ct*16 + (lane & 15);
  int kb   = k0 + (lane >> 4)*8;
  const float* Wp = (c < 64) ? (Wl + c) : (Wr + (c - 64));
  #pragma unroll
  for(int j=0;j<8;j++){
    float v = Wp[(size_t)(kb + j)*H];
    unsigned u = __float_as_uint(v);
    unsigned short hb = (unsigned short)(u >> 16);
    float hv = __uint_as_float(((unsigned)hb) << 16);
    float ev = v - hv;
    unsigned short eb = (unsigned short)(__float_as_uint(ev) >> 16);
    pWh[(size_t)idx*8 + j] = hb;
    pWe[(size_t)idx*8 + j] = eb;
  }
}

// K1: MFMA GEMM  [N,128] @ [128, 64|64] -> xl, xr  via bf16x3 split.
// Register-pressure-controlled rewrite: A-frags converted once (static array);
// outer ct loop (#pragma unroll 2 -> <=2 ct's of b-frags live, 2 MFMA chains);
// per-ct accumulator stored immediately (no acc[8] spanning the kernel).
__global__ __launch_bounds__(256) void k_gemm_mfma(
    const float* __restrict__ x,
    const unsigned short* __restrict__ pWh, const unsigned short* __restrict__ pWe,
    float* __restrict__ xl, float* __restrict__ xr, int N){
  int tid = threadIdx.x;
  int lane = tid & 63, wid = tid >> 6;
  int rowbase = blockIdx.x*64 + wid*16;
  int r = lane & 15, g = lane >> 4;

  int arow = rowbase + r; if(arow > N-1) arow = N-1;   // clamp; bad rows never stored
  const float* xrow = x + (size_t)arow*FIN;

  // A-fragments for all 4 k-steps, hi/lo split (8 s8v = 32 VGPRs, static indexing)
  s8v ah[4], ae[4];
  #pragma unroll
  for(int k0=0;k0<4;k0++){
    float4 va = *(const float4*)(xrow + k0*32 + g*8);
    float4 vb = *(const float4*)(xrow + k0*32 + g*8 + 4);
    float xs_[8] = {va.x,va.y,va.z,va.w,vb.x,vb.y,vb.z,vb.w};
    #pragma unroll
    for(int j=0;j<8;j++){
      unsigned u = __float_as_uint(xs_[j]);
      unsigned short hb = (unsigned short)(u >> 16);
      ah[k0][j] = (short)hb;
      float ev = xs_[j] - __uint_as_float(((unsigned)hb) << 16);
      ae[k0][j] = (short)(unsigned short)(__float_as_uint(ev) >> 16);
    }
  }

  #pragma unroll 2
  for(int ct=0;ct<8;ct++){
    f4v a = (f4v){0.f,0.f,0.f,0.f};
    #pragma unroll
    for(int k0=0;k0<4;k0++){
      size_t boff = ((size_t)(ct*4 + k0)*64 + lane)*8;
      s8v bh = *(const s8v*)(pWh + boff);
      s8v be = *(const s8v*)(pWe + boff);
      a = __builtin_amdgcn_mfma_f32_16x16x32_bf16(ah[k0], bh, a, 0,0,0);
      a = __builtin_amdgcn_mfma_f32_16x16x32_bf16(ah[k0], be, a, 0,0,0);
      a = __builtin_amdgcn_mfma_f32_16x16x32_bf16(ae[k0], bh, a, 0,0,0);
    }
    // store this ct's 16x16 tile: col = (ct&3)*16 + r in xl/xr, rows g*4..g*4+3
    float* dst = (ct < 4) ? xl : xr;
    int cc = (ct & 3)*16 + r;
    #pragma unroll
    for(int rr=0;rr<4;rr++){
      int row = rowbase + g*4 + rr;
      if(row < N) dst[(size_t)row*H + cc] = a[rr];
    }
  }
}

// K2: degree count + per-edge rank (uses the atomic's return value; coalesced rank write)
__global__ void k_degree(const int* __restrict__ ei, int E, int Etot,
                         int* __restrict__ deg, int* __restrict__ rank){
  int i0 = (blockIdx.x*blockDim.x + threadIdx.x)*4;
  if(i0 >= Etot) return;
  if(i0 + 4 <= E && (E & 3) == 0){
    int4 d4 = *(const int4*)(ei + E + i0);
    int r0 = atomicAdd(&deg[d4.x],1);
    int r1 = atomicAdd(&deg[d4.y],1);
    int r2 = atomicAdd(&deg[d4.z],1);
    int r3 = atomicAdd(&deg[d4.w],1);
    *(int4*)(rank + i0) = make_int4(r0,r1,r2,r3);
  } else if(i0 >= E && i0 + 4 <= Etot){
    int v = i0 - E;
    int r0 = atomicAdd(&deg[v+0],1);
    int r1 = atomicAdd(&deg[v+1],1);
    int r2 = atomicAdd(&deg[v+2],1);
    int r3 = atomicAdd(&deg[v+3],1);
    *(int4*)(rank + i0) = make_int4(r0,r1,r2,r3);
  } else {
    #pragma unroll
    for(int q=0;q<4;q++){
      int i = i0+q; if(i>=Etot) break;
      int dst = (i<E) ? ei[E+i] : (i-E);
      rank[i] = atomicAdd(&deg[dst],1);
    }
  }
}

// K3: per-block scan of deg (2048/block), LOCAL-exclusive into rowptr + block totals.
// Last block also writes rowptr[n] = its local total (consumers add bs[n>>11]).
__global__ __launch_bounds__(256) void k_scan_a(const int* __restrict__ deg, int n,
                                                int* __restrict__ rowptr,
                                                int* __restrict__ blocksum){
  __shared__ int wsum[4];
  int tid = threadIdx.x, lane = tid & 63, wid = tid >> 6;
  int idx = blockIdx.x*SCAN_CHUNK + tid*8;
  int v[8];
  if(idx + 8 <= n){
    int4 a = *(const int4*)(deg + idx);
    int4 b = *(const int4*)(deg + idx + 4);
    v[0]=a.x;v[1]=a.y;v[2]=a.z;v[3]=a.w;v[4]=b.x;v[5]=b.y;v[6]=b.z;v[7]=b.w;
  } else {
    #pragma unroll
    for(int i=0;i<8;i++) v[i] = (idx+i<n)? deg[idx+i] : 0;
  }
  int pre[8]; int st=0;
  #pragma unroll
  for(int i=0;i<8;i++){ pre[i]=st; st+=v[i]; }
  int incl = st;
  #pragma unroll
  for(int o=1;o<64;o<<=1){ int u=__shfl_up(incl,o); if(lane>=o) incl+=u; }
  if(lane==63) wsum[wid]=incl;
  __syncthreads();
  if(tid==0){ int accu=0; for(int i=0;i<4;i++){ int t=wsum[i]; wsum[i]=accu; accu+=t; } }
  __syncthreads();
  int toff = wsum[wid] + incl - st;
  if(idx + 8 <= n){
    int4 o0 = make_int4(toff+pre[0],toff+pre[1],toff+pre[2],toff+pre[3]);
    int4 o1 = make_int4(toff+pre[4],toff+pre[5],toff+pre[6],toff+pre[7]);
    *(int4*)(rowptr+idx)=o0; *(int4*)(rowptr+idx+4)=o1;
  } else {
    #pragma unroll
    for(int i=0;i<8;i++) if(idx+i<n) rowptr[idx+i]=toff+pre[i];
  }
  if(tid==255){
    blocksum[blockIdx.x] = toff + st;
    if(blockIdx.x == gridDim.x-1) rowptr[n] = toff + st;
  }
}

// K4: CSR fill — no atomics; p = rowptr_local[dst] + bs[dst>>11] + rank[i]
__global__ void k_fill(const int* __restrict__ ei, int E, int Etot,
                       const int* __restrict__ rowptr,
                       const int* __restrict__ blocksum, int nscan,
                       const int* __restrict__ rank, int* __restrict__ csr_src){
  __shared__ int bs[64];
  int tid = threadIdx.x;
  load_bs(blocksum, nscan, bs, tid);
  int i0 = (blockIdx.x*blockDim.x + tid)*4;
  if(i0 >= Etot) return;
  if(i0 + 4 <= E && (E & 3) == 0){
    int4 s4 = *(const int4*)(ei + i0);
    int4 d4 = *(const int4*)(ei + E + i0);
    int4 r4 = *(const int4*)(rank + i0);
    csr_src[rowptr[d4.x] + bs[d4.x>>11] + r4.x] = s4.x;
    csr_src[rowptr[d4.y] + bs[d4.y>>11] + r4.y] = s4.y;
    csr_src[rowptr[d4.z] + bs[d4.z>>11] + r4.z] = s4.z;
    csr_src[rowptr[d4.w] + bs[d4.w>>11] + r4.w] = s4.w;
  } else if(i0 >= E && i0 + 4 <= Etot){
    int4 r4 = *(const int4*)(rank + i0);
    int v = i0 - E;
    csr_src[rowptr[v+0] + bs[(v+0)>>11] + r4.x] = v+0;
    csr_src[rowptr[v+1] + bs[(v+1)>>11] + r4.y] = v+1;
    csr_src[rowptr[v+2] + bs[(v+2)>>11] + r4.z] = v+2;
    csr_src[rowptr[v+3] + bs[(v+3)>>11] + r4.w] = v+3;
  } else {
    #pragma unroll
    for(int q=0;q<4;q++){
      int i = i0+q; if(i>=Etot) break;
      int src, dst;
      if(i<E){ src = ei[i]; dst = ei[E+i]; } else { src = i-E; dst = i-E; }
      csr_src[rowptr[dst] + bs[dst>>11] + rank[i]] = src;
    }
  }
}

// K5: fused layer-1 (no-max softmax).  16-lane group per node, 4 nodes/wave.
// Chunk-of-8 edges: all 8 csr_src loads + 8 xl gathers issued before consumption.
__global__ void k_node1f(const int* __restrict__ rowptr, const int* __restrict__ blocksum,
                         int nscan, const int* __restrict__ csr_src,
                         const float* __restrict__ xl, const float* __restrict__ xr,
                         const float* __restrict__ att, const float* __restrict__ b1,
                         const float* __restrict__ Wl2, const float* __restrict__ Wr2,
                         float* __restrict__ xl2, float* __restrict__ xr2, int N){
  __shared__ int bs[64];
  int tid = threadIdx.x;
  load_bs(blocksum, nscan, bs, tid);
  int node = blockIdx.x*16 + (tid>>4);
  int gl = tid & 15;
  if(node >= N) return;
  int f4 = gl*4;
  float4 attv = *(const float4*)(att + f4);
  float4 xrv  = *(const float4*)(xr + (size_t)node*H + f4);
  int s = rowptr[node]   + bs[node>>11];
  int t = rowptr[node+1] + bs[(node+1)>>11];
  float d = 0.f;
  float ax=0.f, ay=0.f, az=0.f, aw=0.f;

  for(int k=s; k<t; k+=8){
    int tl = t - 1;
    int ks[8]; float4 xv[8]; float msk[8];
    #pragma unroll
    for(int j=0;j<8;j++){
      int kj = k + j;
      ks[j] = (kj < t) ? kj : tl;
      msk[j] = (kj < t) ? 1.f : 0.f;
    }
    int ss[8];
    #pragma unroll
    for(int j=0;j<8;j++) ss[j] = csr_src[ks[j]];
    #pragma unroll
    for(int j=0;j<8;j++) xv[j] = *(const float4*)(xl + (size_t)ss[j]*H + f4);
    #pragma unroll
    for(int j=0;j<8;j++){
      float h0 = xv[j].x + xrv.x, h1 = xv[j].y + xrv.y;
      float h2 = xv[j].z + xrv.z, h3 = xv[j].w + xrv.w;
      float l0 = (h0>0.f)? h0 : NEG_SLOPE*h0;
      float l1 = (h1>0.f)? h1 : NEG_SLOPE*h1;
      float l2 = (h2>0.f)? h2 : NEG_SLOPE*h2;
      float l3 = (h3>0.f)? h3 : NEG_SLOPE*h3;
      float e = l0*attv.x + l1*attv.y + l2*attv.z + l3*attv.w;
      #pragma unroll
      for(int o=1;o<16;o<<=1) e += __shfl_xor(e,o);
      float w = msk[j] * __expf(e);
      d  += w;
      ax += w*xv[j].x; ay += w*xv[j].y; az += w*xv[j].z; aw += w*xv[j].w;
    }
  }

  float inv = 1.f/(d + EPS);
  float4 bv = *(const float4*)(b1 + f4);
  float h0 = ax*inv + bv.x, h1 = ay*inv + bv.y;
  float h2 = az*inv + bv.z, h3 = aw*inv + bv.w;
  float p0 = h0*Wl2[(f4+0)*FOUT+0] + h1*Wl2[(f4+1)*FOUT+0] + h2*Wl2[(f4+2)*FOUT+0] + h3*Wl2[(f4+3)*FOUT+0];
  float p1 = h0*Wl2[(f4+0)*FOUT+1] + h1*Wl2[(f4+1)*FOUT+1] + h2*Wl2[(f4+2)*FOUT+1] + h3*Wl2[(f4+3)*FOUT+1];
  float p2 = h0*Wr2[(f4+0)*FOUT+0] + h1*Wr2[(f4+1)*FOUT+0] + h2*Wr2[(f4+2)*FOUT+0] + h3*Wr2[(f4+3)*FOUT+0];
  float p3 = h0*Wr2[(f4+0)*FOUT+1] + h1*Wr2[(f4+1)*FOUT+1] + h2*Wr2[(f4+2)*FOUT+1] + h3*Wr2[(f4+3)*FOUT+1];
  #pragma unroll
  for(int o=1;o<16;o<<=1){
    p0 += __shfl_xor(p0,o); p1 += __shfl_xor(p1,o);
    p2 += __shfl_xor(p2,o); p3 += __shfl_xor(p3,o);
  }
  if(gl==0){
    *(float2*)(xl2 + node*2) = make_float2(p0,p1);
    *(float2*)(xr2 + node*2) = make_float2(p2,p3);
  }
}

// K6: layer-2 full conv, single pass (no-max), 16-lane group per node, 4 nodes/wave
__global__ void k_node2(const int* __restrict__ rowptr, const int* __restrict__ blocksum,
                        int nscan, const int* __restrict__ csr_src,
                        const float* __restrict__ xl2, const float* __restrict__ xr2,
                        const float* __restrict__ att2, const float* __restrict__ b2,
                        float* __restrict__ out, int N){
  __shared__ int bs[64];
  int tid = threadIdx.x;
  load_bs(blocksum, nscan, bs, tid);
  int node = blockIdx.x*16 + (tid>>4);
  int gl = tid & 15;
  if(node >= N) return;
  int s = rowptr[node]   + bs[node>>11];
  int t = rowptr[node+1] + bs[(node+1)>>11];
  float2 xrv = *(const float2*)(xr2 + node*2);
  float a0 = att2[0], a1 = att2[1];
  float den=0.f, n0=0.f, n1=0.f;
  for(int k=s+gl; k<t; k+=16){
    int src = csr_src[k];
    float2 xs = *(const float2*)(xl2 + src*2);
    float h0 = xs.x + xrv.x, h1 = xs.y + xrv.y;
    float l0 = (h0>0.f)? h0 : NEG_SLOPE*h0;
    float l1 = (h1>0.f)? h1 : NEG_SLOPE*h1;
    float ex = __expf(l0*a0 + l1*a1);
    den += ex; n0 += ex*xs.x; n1 += ex*xs.y;
  }
  #pragma unroll
  for(int o=1;o<16;o<<=1){
    den += __shfl_xor(den,o);
    n0  += __shfl_xor(n0,o);
    n1  += __shfl_xor(n1,o);
  }
  if(gl==0){
    float inv = 1.f/(den + EPS);
    out[node*2+0] = n0*inv + b2[0];
    out[node*2+1] = n1*inv + b2[1];
  }
}

extern "C" void kernel_launch(void* const* d_in, const int* in_sizes, int n_in,
                              void* d_out, int out_size, void* d_ws, size_t ws_size,
                              hipStream_t stream){
  const float* x    = (const float*)d_in[0];
  const int*   ei   = (const int*)d_in[1];
  const float* Wl1  = (const float*)d_in[2];
  const float* Wr1  = (const float*)d_in[3];
  const float* att1 = (const float*)d_in[4];
  const float* b1   = (const float*)d_in[5];
  const float* Wl2  = (const float*)d_in[6];
  const float* Wr2  = (const float*)d_in[7];
  const float* att2 = (const float*)d_in[8];
  const float* b2   = (const float*)d_in[9];
  int N = in_sizes[0]/FIN;
  int E = in_sizes[1]/2;
  int Etot = E + N;
  int nscan = (N + SCAN_CHUNK - 1) / SCAN_CHUNK;   // 25 for N=50000 (<=64 required)
  int nquad = (Etot + 3) / 4;
  int ZB = (N + 255) / 256;                        // zero-part blocks in k_prep

  char* w = (char*)d_ws;
  size_t off = 0;
  auto alloc = [&](size_t bytes)->void*{
    void* p = w + off;
    off = (off + bytes + 255) & ~(size_t)255;
    return p;
  };
  float* xl1     = (float*)alloc((size_t)N*H*4);
  float* xr1     = (float*)alloc((size_t)N*H*4);
  int*   csr_src = (int*)  alloc((size_t)Etot*4);
  int*   rank    = (int*)  alloc((size_t)Etot*4);
  int*   deg     = (int*)  alloc((size_t)N*4);
  int*   rowptr  = (int*)  alloc((size_t)(N+1)*4);
  int*   blocksum= (int*)  alloc((size_t)64*4);
  float* xl2     = (float*)alloc((size_t)N*2*4);
  float* xr2     = (float*)alloc((size_t)N*2*4);
  unsigned short* pWh = (unsigned short*)alloc((size_t)2048*8*2);
  unsigned short* pWe = (unsigned short*)alloc((size_t)2048*8*2);

  k_prep<<<ZB+8, 256, 0, stream>>>(deg, N, ZB, Wl1, Wr1, pWh, pWe);
  k_gemm_mfma<<<(N+63)/64, 256, 0, stream>>>(x, pWh, pWe, xl1, xr1, N);
  k_degree<<<(nquad+255)/256,256,0,stream>>>(ei, E, Etot, deg, rank);
  k_scan_a<<<nscan,256,0,stream>>>(deg, N, rowptr, blocksum);
  k_fill<<<(nquad+255)/256,256,0,stream>>>(ei, E, Etot, rowptr, blocksum, nscan, rank, csr_src);
  k_node1f<<<(N+15)/16, 256, 0, stream>>>(rowptr, blocksum, nscan, csr_src,
                                          xl1, xr1, att1, b1, Wl2, Wr2, xl2, xr2, N);
  k_node2<<<(N+15)/16, 256, 0, stream>>>(rowptr, blocksum, nscan, csr_src,
                                         xl2, xr2, att2, b2, (float*)d_out, N);
}

// Round 13
// 123.625 us; speedup vs baseline: 1.0939x; 1.0181x over previous
//
#include <hip/hip_runtime.h>
#include <math.h>

#define FIN 128
#define H 64
#define FOUT 2
#define NEG_SLOPE 0.2f
#define EPS 1e-16f

#define SCAN_CHUNK 2048   // elements per scan_a block (256 thr * 8)

typedef __attribute__((ext_vector_type(8))) short s8v;   // 8 bf16 (4 VGPR)
typedef __attribute__((ext_vector_type(4))) float f4v;   // MFMA acc

// Preamble: exclusive scan of blocksum[0..nscan) into LDS bs[] (nscan <= 64).
__device__ __forceinline__ void load_bs(const int* __restrict__ blocksum, int nscan,
                                        int* bs, int tid){
  if(tid < 64){
    int v = (tid < nscan)? blocksum[tid] : 0;
    int incl = v;
    #pragma unroll
    for(int o=1;o<64;o<<=1){ int u=__shfl_up(incl,o); if(tid>=o) incl+=u; }
    bs[tid] = incl - v;
  }
  __syncthreads();
}

// K0: fused [zero deg] + [pack W into MFMA B-fragments, split hi/lo bf16].
__global__ void k_prep(int* __restrict__ deg, int N, int ZB,
                       const float* __restrict__ Wl, const float* __restrict__ Wr,
                       unsigned short* __restrict__ pWh, unsigned short* __restrict__ pWe){
  int b = blockIdx.x;
  if(b < ZB){
    int i = b*256 + threadIdx.x;
    if(i < N) deg[i] = 0;
    return;
  }
  int idx = (b - ZB)*256 + threadIdx.x;     // (ct*4+k0)*64 + lane, < 2048
  int lane = idx & 63;
  int ctk  = idx >> 6;
  int k0   = (ctk & 3) * 32;
  int ct   = ctk >> 2;
  int c    = ct*16 + (lane & 15);
  int kb   = k0 + (lane >> 4)*8;
  const float* Wp = (c < 64) ? (Wl + c) : (Wr + (c - 64));
  #pragma unroll
  for(int j=0;j<8;j++){
    float v = Wp[(size_t)(kb + j)*H];
    unsigned u = __float_as_uint(v);
    unsigned short hb = (unsigned short)(u >> 16);
    float hv = __uint_as_float(((unsigned)hb) << 16);
    float ev = v - hv;
    unsigned short eb = (unsigned short)(__float_as_uint(ev) >> 16);
    pWh[(size_t)idx*8 + j] = hb;
    pWe[(size_t)idx*8 + j] = eb;
  }
}

// K1: MFMA GEMM [N,128]@[128,64|64] -> xl, xr (fp32) + xlb (bf16 shadow of xl).
__global__ __launch_bounds__(256) void k_gemm_mfma(
    const float* __restrict__ x,
    const unsigned short* __restrict__ pWh, const unsigned short* __restrict__ pWe,
    float* __restrict__ xl, float* __restrict__ xr,
    unsigned short* __restrict__ xlb, int N){
  int tid = threadIdx.x;
  int lane = tid & 63, wid = tid >> 6;
  int rowbase = blockIdx.x*64 + wid*16;
  int r = lane & 15, g = lane >> 4;

  int arow = rowbase + r; if(arow > N-1) arow = N-1;
  const float* xrow = x + (size_t)arow*FIN;

  s8v ah[4], ae[4];
  #pragma unroll
  for(int k0=0;k0<4;k0++){
    float4 va = *(const float4*)(xrow + k0*32 + g*8);
    float4 vb = *(const float4*)(xrow + k0*32 + g*8 + 4);
    float xs_[8] = {va.x,va.y,va.z,va.w,vb.x,vb.y,vb.z,vb.w};
    #pragma unroll
    for(int j=0;j<8;j++){
      unsigned u = __float_as_uint(xs_[j]);
      unsigned short hb = (unsigned short)(u >> 16);
      ah[k0][j] = (short)hb;
      float ev = xs_[j] - __uint_as_float(((unsigned)hb) << 16);
      ae[k0][j] = (short)(unsigned short)(__float_as_uint(ev) >> 16);
    }
  }

  #pragma unroll 2
  for(int ct=0;ct<8;ct++){
    f4v a = (f4v){0.f,0.f,0.f,0.f};
    #pragma unroll
    for(int k0=0;k0<4;k0++){
      size_t boff = ((size_t)(ct*4 + k0)*64 + lane)*8;
      s8v bh = *(const s8v*)(pWh + boff);
      s8v be = *(const s8v*)(pWe + boff);
      a = __builtin_amdgcn_mfma_f32_16x16x32_bf16(ah[k0], bh, a, 0,0,0);
      a = __builtin_amdgcn_mfma_f32_16x16x32_bf16(ah[k0], be, a, 0,0,0);
      a = __builtin_amdgcn_mfma_f32_16x16x32_bf16(ae[k0], bh, a, 0,0,0);
    }
    float* dst = (ct < 4) ? xl : xr;
    int cc = (ct & 3)*16 + r;
    #pragma unroll
    for(int rr=0;rr<4;rr++){
      int row = rowbase + g*4 + rr;
      if(row < N){
        dst[(size_t)row*H + cc] = a[rr];
        if(ct < 4){
          unsigned u = __float_as_uint(a[rr]);
          xlb[(size_t)row*H + cc] = (unsigned short)((u + 0x7FFF + ((u>>16)&1)) >> 16); // RNE
        }
      }
    }
  }
}

// K2: degree count + per-edge rank
__global__ void k_degree(const int* __restrict__ ei, int E, int Etot,
                         int* __restrict__ deg, int* __restrict__ rank){
  int i0 = (blockIdx.x*blockDim.x + threadIdx.x)*4;
  if(i0 >= Etot) return;
  if(i0 + 4 <= E && (E & 3) == 0){
    int4 d4 = *(const int4*)(ei + E + i0);
    int r0 = atomicAdd(&deg[d4.x],1);
    int r1 = atomicAdd(&deg[d4.y],1);
    int r2 = atomicAdd(&deg[d4.z],1);
    int r3 = atomicAdd(&deg[d4.w],1);
    *(int4*)(rank + i0) = make_int4(r0,r1,r2,r3);
  } else if(i0 >= E && i0 + 4 <= Etot){
    int v = i0 - E;
    int r0 = atomicAdd(&deg[v+0],1);
    int r1 = atomicAdd(&deg[v+1],1);
    int r2 = atomicAdd(&deg[v+2],1);
    int r3 = atomicAdd(&deg[v+3],1);
    *(int4*)(rank + i0) = make_int4(r0,r1,r2,r3);
  } else {
    #pragma unroll
    for(int q=0;q<4;q++){
      int i = i0+q; if(i>=Etot) break;
      int dst = (i<E) ? ei[E+i] : (i-E);
      rank[i] = atomicAdd(&deg[dst],1);
    }
  }
}

// K3: per-block scan of deg, LOCAL-exclusive into rowptr + block totals.
__global__ __launch_bounds__(256) void k_scan_a(const int* __restrict__ deg, int n,
                                                int* __restrict__ rowptr,
                                                int* __restrict__ blocksum){
  __shared__ int wsum[4];
  int tid = threadIdx.x, lane = tid & 63, wid = tid >> 6;
  int idx = blockIdx.x*SCAN_CHUNK + tid*8;
  int v[8];
  if(idx + 8 <= n){
    int4 a = *(const int4*)(deg + idx);
    int4 b = *(const int4*)(deg + idx + 4);
    v[0]=a.x;v[1]=a.y;v[2]=a.z;v[3]=a.w;v[4]=b.x;v[5]=b.y;v[6]=b.z;v[7]=b.w;
  } else {
    #pragma unroll
    for(int i=0;i<8;i++) v[i] = (idx+i<n)? deg[idx+i] : 0;
  }
  int pre[8]; int st=0;
  #pragma unroll
  for(int i=0;i<8;i++){ pre[i]=st; st+=v[i]; }
  int incl = st;
  #pragma unroll
  for(int o=1;o<64;o<<=1){ int u=__shfl_up(incl,o); if(lane>=o) incl+=u; }
  if(lane==63) wsum[wid]=incl;
  __syncthreads();
  if(tid==0){ int accu=0; for(int i=0;i<4;i++){ int t=wsum[i]; wsum[i]=accu; accu+=t; } }
  __syncthreads();
  int toff = wsum[wid] + incl - st;
  if(idx + 8 <= n){
    int4 o0 = make_int4(toff+pre[0],toff+pre[1],toff+pre[2],toff+pre[3]);
    int4 o1 = make_int4(toff+pre[4],toff+pre[5],toff+pre[6],toff+pre[7]);
    *(int4*)(rowptr+idx)=o0; *(int4*)(rowptr+idx+4)=o1;
  } else {
    #pragma unroll
    for(int i=0;i<8;i++) if(idx+i<n) rowptr[idx+i]=toff+pre[i];
  }
  if(tid==255){
    blocksum[blockIdx.x] = toff + st;
    if(blockIdx.x == gridDim.x-1) rowptr[n] = toff + st;
  }
}

// K4: CSR fill — no atomics; p = rowptr_local[dst] + bs[dst>>11] + rank[i]
__global__ void k_fill(const int* __restrict__ ei, int E, int Etot,
                       const int* __restrict__ rowptr,
                       const int* __restrict__ blocksum, int nscan,
                       const int* __restrict__ rank, int* __restrict__ csr_src){
  __shared__ int bs[64];
  int tid = threadIdx.x;
  load_bs(blocksum, nscan, bs, tid);
  int i0 = (blockIdx.x*blockDim.x + tid)*4;
  if(i0 >= Etot) return;
  if(i0 + 4 <= E && (E & 3) == 0){
    int4 s4 = *(const int4*)(ei + i0);
    int4 d4 = *(const int4*)(ei + E + i0);
    int4 r4 = *(const int4*)(rank + i0);
    csr_src[rowptr[d4.x] + bs[d4.x>>11] + r4.x] = s4.x;
    csr_src[rowptr[d4.y] + bs[d4.y>>11] + r4.y] = s4.y;
    csr_src[rowptr[d4.z] + bs[d4.z>>11] + r4.z] = s4.z;
    csr_src[rowptr[d4.w] + bs[d4.w>>11] + r4.w] = s4.w;
  } else if(i0 >= E && i0 + 4 <= Etot){
    int4 r4 = *(const int4*)(rank + i0);
    int v = i0 - E;
    csr_src[rowptr[v+0] + bs[(v+0)>>11] + r4.x] = v+0;
    csr_src[rowptr[v+1] + bs[(v+1)>>11] + r4.y] = v+1;
    csr_src[rowptr[v+2] + bs[(v+2)>>11] + r4.z] = v+2;
    csr_src[rowptr[v+3] + bs[(v+3)>>11] + r4.w] = v+3;
  } else {
    #pragma unroll
    for(int q=0;q<4;q++){
      int i = i0+q; if(i>=Etot) break;
      int src, dst;
      if(i<E){ src = ei[i]; dst = ei[E+i]; } else { src = i-E; dst = i-E; }
      csr_src[rowptr[dst] + bs[dst>>11] + rank[i]] = src;
    }
  }
}

// K5: fused layer-1 (no-max softmax).  16-lane group per node, 4 nodes/wave.
// Gathers xl in BF16 (8B/lane/edge — halves gather traffic + cache footprint).
__global__ void k_node1f(const int* __restrict__ rowptr, const int* __restrict__ blocksum,
                         int nscan, const int* __restrict__ csr_src,
                         const unsigned short* __restrict__ xlb, const float* __restrict__ xr,
                         const float* __restrict__ att, const float* __restrict__ b1,
                         const float* __restrict__ Wl2, const float* __restrict__ Wr2,
                         float* __restrict__ xl2, float* __restrict__ xr2, int N){
  __shared__ int bs[64];
  int tid = threadIdx.x;
  load_bs(blocksum, nscan, bs, tid);
  int node = blockIdx.x*16 + (tid>>4);
  int gl = tid & 15;
  if(node >= N) return;
  int f4 = gl*4;
  float4 attv = *(const float4*)(att + f4);
  float4 xrv  = *(const float4*)(xr + (size_t)node*H + f4);
  int s = rowptr[node]   + bs[node>>11];
  int t = rowptr[node+1] + bs[(node+1)>>11];
  float d = 0.f;
  float ax=0.f, ay=0.f, az=0.f, aw=0.f;

  for(int k=s; k<t; k+=8){
    int tl = t - 1;
    int ks[8]; float4 xv[8]; float msk[8];
    #pragma unroll
    for(int j=0;j<8;j++){
      int kj = k + j;
      ks[j] = (kj < t) ? kj : tl;
      msk[j] = (kj < t) ? 1.f : 0.f;
    }
    int ss[8];
    #pragma unroll
    for(int j=0;j<8;j++) ss[j] = csr_src[ks[j]];
    #pragma unroll
    for(int j=0;j<8;j++){
      ushort4 uv = *(const ushort4*)(xlb + (size_t)ss[j]*H + f4);
      xv[j].x = __uint_as_float((unsigned)uv.x << 16);
      xv[j].y = __uint_as_float((unsigned)uv.y << 16);
      xv[j].z = __uint_as_float((unsigned)uv.z << 16);
      xv[j].w = __uint_as_float((unsigned)uv.w << 16);
    }
    #pragma unroll
    for(int j=0;j<8;j++){
      float h0 = xv[j].x + xrv.x, h1 = xv[j].y + xrv.y;
      float h2 = xv[j].z + xrv.z, h3 = xv[j].w + xrv.w;
      float l0 = (h0>0.f)? h0 : NEG_SLOPE*h0;
      float l1 = (h1>0.f)? h1 : NEG_SLOPE*h1;
      float l2 = (h2>0.f)? h2 : NEG_SLOPE*h2;
      float l3 = (h3>0.f)? h3 : NEG_SLOPE*h3;
      float e = l0*attv.x + l1*attv.y + l2*attv.z + l3*attv.w;
      #pragma unroll
      for(int o=1;o<16;o<<=1) e += __shfl_xor(e,o);
      float w = msk[j] * __expf(e);
      d  += w;
      ax += w*xv[j].x; ay += w*xv[j].y; az += w*xv[j].z; aw += w*xv[j].w;
    }
  }

  float inv = 1.f/(d + EPS);
  float4 bv = *(const float4*)(b1 + f4);
  float h0 = ax*inv + bv.x, h1 = ay*inv + bv.y;
  float h2 = az*inv + bv.z, h3 = aw*inv + bv.w;
  float p0 = h0*Wl2[(f4+0)*FOUT+0] + h1*Wl2[(f4+1)*FOUT+0] + h2*Wl2[(f4+2)*FOUT+0] + h3*Wl2[(f4+3)*FOUT+0];
  float p1 = h0*Wl2[(f4+0)*FOUT+1] + h1*Wl2[(f4+1)*FOUT+1] + h2*Wl2[(f4+2)*FOUT+1] + h3*Wl2[(f4+3)*FOUT+1];
  float p2 = h0*Wr2[(f4+0)*FOUT+0] + h1*Wr2[(f4+1)*FOUT+0] + h2*Wr2[(f4+2)*FOUT+0] + h3*Wr2[(f4+3)*FOUT+0];
  float p3 = h0*Wr2[(f4+0)*FOUT+1] + h1*Wr2[(f4+1)*FOUT+1] + h2*Wr2[(f4+2)*FOUT+1] + h3*Wr2[(f4+3)*FOUT+1];
  #pragma unroll
  for(int o=1;o<16;o<<=1){
    p0 += __shfl_xor(p0,o); p1 += __shfl_xor(p1,o);
    p2 += __shfl_xor(p2,o); p3 += __shfl_xor(p3,o);
  }
  if(gl==0){
    *(float2*)(xl2 + node*2) = make_float2(p0,p1);
    *(float2*)(xr2 + node*2) = make_float2(p2,p3);
  }
}

// K6: layer-2 full conv, single pass (no-max), 16-lane group per node, 4 nodes/wave
__global__ void k_node2(const int* __restrict__ rowptr, const int* __restrict__ blocksum,
                        int nscan, const int* __restrict__ csr_src,
                        const float* __restrict__ xl2, const float* __restrict__ xr2,
                        const float* __restrict__ att2, const float* __restrict__ b2,
                        float* __restrict__ out, int N){
  __shared__ int bs[64];
  int tid = threadIdx.x;
  load_bs(blocksum, nscan, bs, tid);
  int node = blockIdx.x*16 + (tid>>4);
  int gl = tid & 15;
  if(node >= N) return;
  int s = rowptr[node]   + bs[node>>11];
  int t = rowptr[node+1] + bs[(node+1)>>11];
  float2 xrv = *(const float2*)(xr2 + node*2);
  float a0 = att2[0], a1 = att2[1];
  float den=0.f, n0=0.f, n1=0.f;
  for(int k=s+gl; k<t; k+=16){
    int src = csr_src[k];
    float2 xs = *(const float2*)(xl2 + src*2);
    float h0 = xs.x + xrv.x, h1 = xs.y + xrv.y;
    float l0 = (h0>0.f)? h0 : NEG_SLOPE*h0;
    float l1 = (h1>0.f)? h1 : NEG_SLOPE*h1;
    float ex = __expf(l0*a0 + l1*a1);
    den += ex; n0 += ex*xs.x; n1 += ex*xs.y;
  }
  #pragma unroll
  for(int o=1;o<16;o<<=1){
    den += __shfl_xor(den,o);
    n0  += __shfl_xor(n0,o);
    n1  += __shfl_xor(n1,o);
  }
  if(gl==0){
    float inv = 1.f/(den + EPS);
    out[node*2+0] = n0*inv + b2[0];
    out[node*2+1] = n1*inv + b2[1];
  }
}

extern "C" void kernel_launch(void* const* d_in, const int* in_sizes, int n_in,
                              void* d_out, int out_size, void* d_ws, size_t ws_size,
                              hipStream_t stream){
  const float* x    = (const float*)d_in[0];
  const int*   ei   = (const int*)d_in[1];
  const float* Wl1  = (const float*)d_in[2];
  const float* Wr1  = (const float*)d_in[3];
  const float* att1 = (const float*)d_in[4];
  const float* b1   = (const float*)d_in[5];
  const float* Wl2  = (const float*)d_in[6];
  const float* Wr2  = (const float*)d_in[7];
  const float* att2 = (const float*)d_in[8];
  const float* b2   = (const float*)d_in[9];
  int N = in_sizes[0]/FIN;
  int E = in_sizes[1]/2;
  int Etot = E + N;
  int nscan = (N + SCAN_CHUNK - 1) / SCAN_CHUNK;   // 25 for N=50000 (<=64 required)
  int nquad = (Etot + 3) / 4;
  int ZB = (N + 255) / 256;

  char* w = (char*)d_ws;
  size_t off = 0;
  auto alloc = [&](size_t bytes)->void*{
    void* p = w + off;
    off = (off + bytes + 255) & ~(size_t)255;
    return p;
  };
  float* xl1     = (float*)alloc((size_t)N*H*4);
  float* xr1     = (float*)alloc((size_t)N*H*4);
  unsigned short* xlb = (unsigned short*)alloc((size_t)N*H*2);
  int*   csr_src = (int*)  alloc((size_t)Etot*4);
  int*   rank    = (int*)  alloc((size_t)Etot*4);
  int*   deg     = (int*)  alloc((size_t)N*4);
  int*   rowptr  = (int*)  alloc((size_t)(N+1)*4);
  int*   blocksum= (int*)  alloc((size_t)64*4);
  float* xl2     = (float*)alloc((size_t)N*2*4);
  float* xr2     = (float*)alloc((size_t)N*2*4);
  unsigned short* pWh = (unsigned short*)alloc((size_t)2048*8*2);
  unsigned short* pWe = (unsigned short*)alloc((size_t)2048*8*2);

  k_prep<<<ZB+8, 256, 0, stream>>>(deg, N, ZB, Wl1, Wr1, pWh, pWe);
  k_gemm_mfma<<<(N+63)/64, 256, 0, stream>>>(x, pWh, pWe, xl1, xr1, xlb, N);
  k_degree<<<(nquad+255)/256,256,0,stream>>>(ei, E, Etot, deg, rank);
  k_scan_a<<<nscan,256,0,stream>>>(deg, N, rowptr, blocksum);
  k_fill<<<(nquad+255)/256,256,0,stream>>>(ei, E, Etot, rowptr, blocksum, nscan, rank, csr_src);
  k_node1f<<<(N+15)/16, 256, 0, stream>>>(rowptr, blocksum, nscan, csr_src,
                                          xlb, xr1, att1, b1, Wl2, Wr2, xl2, xr2, N);
  k_node2<<<(N+15)/16, 256, 0, stream>>>(rowptr, blocksum, nscan, csr_src,
                                         xl2, xr2, att2, b2, (float*)d_out, N);
}

// Round 14
// 122.111 us; speedup vs baseline: 1.1075x; 1.0124x over previous
//
#include <hip/hip_runtime.h>
#include <math.h>

#define FIN 128
#define H 64
#define FOUT 2
#define NEG_SLOPE 0.2f
#define EPS 1e-16f

#define SCAN_CHUNK 2048   // elements per scan_a block (256 thr * 8)

typedef __attribute__((ext_vector_type(8))) short s8v;   // 8 bf16 (4 VGPR)
typedef __attribute__((ext_vector_type(4))) float f4v;   // MFMA acc

// Preamble: exclusive scan of blocksum[0..nscan) into LDS bs[] (nscan <= 64).
__device__ __forceinline__ void load_bs(const int* __restrict__ blocksum, int nscan,
                                        int* bs, int tid){
  if(tid < 64){
    int v = (tid < nscan)? blocksum[tid] : 0;
    int incl = v;
    #pragma unroll
    for(int o=1;o<64;o<<=1){ int u=__shfl_up(incl,o); if(tid>=o) incl+=u; }
    bs[tid] = incl - v;
  }
  __syncthreads();
}

// K0: fused [zero deg] + [pack W into MFMA B-fragments, split hi/lo bf16].
__global__ void k_prep(int* __restrict__ deg, int N, int ZB,
                       const float* __restrict__ Wl, const float* __restrict__ Wr,
                       unsigned short* __restrict__ pWh, unsigned short* __restrict__ pWe){
  int b = blockIdx.x;
  if(b < ZB){
    int i = b*256 + threadIdx.x;
    if(i < N) deg[i] = 0;
    return;
  }
  int idx = (b - ZB)*256 + threadIdx.x;     // (ct*4+k0)*64 + lane, < 2048
  int lane = idx & 63;
  int ctk  = idx >> 6;
  int k0   = (ctk & 3) * 32;
  int ct   = ctk >> 2;
  int c    = ct*16 + (lane & 15);
  int kb   = k0 + (lane >> 4)*8;
  const float* Wp = (c < 64) ? (Wl + c) : (Wr + (c - 64));
  #pragma unroll
  for(int j=0;j<8;j++){
    float v = Wp[(size_t)(kb + j)*H];
    unsigned u = __float_as_uint(v);
    unsigned short hb = (unsigned short)(u >> 16);
    float hv = __uint_as_float(((unsigned)hb) << 16);
    float ev = v - hv;
    unsigned short eb = (unsigned short)(__float_as_uint(ev) >> 16);
    pWh[(size_t)idx*8 + j] = hb;
    pWe[(size_t)idx*8 + j] = eb;
  }
}

// K1: FUSED [MFMA GEMM (blocks 0..GG-1)] || [degree+rank 8-wide (blocks GG..)].
// Both depend only on k_prep; neither uses LDS -> no occupancy coupling (R10's confound).
__global__ __launch_bounds__(256) void k_gemm_deg(
    const float* __restrict__ x,
    const unsigned short* __restrict__ pWh, const unsigned short* __restrict__ pWe,
    float* __restrict__ xl, float* __restrict__ xr,
    unsigned short* __restrict__ xlb, int N, int GG,
    const int* __restrict__ ei, int E, int Etot,
    int* __restrict__ deg, int* __restrict__ rank){
  int tid = threadIdx.x;
  if((int)blockIdx.x >= GG){
    // ---- degree + rank, 8 edges/thread (8 atomics in flight) ----
    int i0 = (((int)blockIdx.x - GG)*256 + tid)*8;
    if(i0 >= Etot) return;
    if(i0 + 8 <= E && (E & 3) == 0){
      int4 da = *(const int4*)(ei + E + i0);
      int4 db = *(const int4*)(ei + E + i0 + 4);
      int r0 = atomicAdd(&deg[da.x],1);
      int r1 = atomicAdd(&deg[da.y],1);
      int r2 = atomicAdd(&deg[da.z],1);
      int r3 = atomicAdd(&deg[da.w],1);
      int r4 = atomicAdd(&deg[db.x],1);
      int r5 = atomicAdd(&deg[db.y],1);
      int r6 = atomicAdd(&deg[db.z],1);
      int r7 = atomicAdd(&deg[db.w],1);
      *(int4*)(rank + i0)     = make_int4(r0,r1,r2,r3);
      *(int4*)(rank + i0 + 4) = make_int4(r4,r5,r6,r7);
    } else if(i0 >= E && i0 + 8 <= Etot){
      int v = i0 - E;
      int r0 = atomicAdd(&deg[v+0],1);
      int r1 = atomicAdd(&deg[v+1],1);
      int r2 = atomicAdd(&deg[v+2],1);
      int r3 = atomicAdd(&deg[v+3],1);
      int r4 = atomicAdd(&deg[v+4],1);
      int r5 = atomicAdd(&deg[v+5],1);
      int r6 = atomicAdd(&deg[v+6],1);
      int r7 = atomicAdd(&deg[v+7],1);
      *(int4*)(rank + i0)     = make_int4(r0,r1,r2,r3);
      *(int4*)(rank + i0 + 4) = make_int4(r4,r5,r6,r7);
    } else {
      #pragma unroll
      for(int q=0;q<8;q++){
        int i = i0+q; if(i>=Etot) break;
        int dst = (i<E) ? ei[E+i] : (i-E);
        rank[i] = atomicAdd(&deg[dst],1);
      }
    }
    return;
  }

  // ---- MFMA GEMM part (bf16x3 split) ----
  int lane = tid & 63, wid = tid >> 6;
  int rowbase = blockIdx.x*64 + wid*16;
  int r = lane & 15, g = lane >> 4;

  int arow = rowbase + r; if(arow > N-1) arow = N-1;
  const float* xrow = x + (size_t)arow*FIN;

  s8v ah[4], ae[4];
  #pragma unroll
  for(int k0=0;k0<4;k0++){
    float4 va = *(const float4*)(xrow + k0*32 + g*8);
    float4 vb = *(const float4*)(xrow + k0*32 + g*8 + 4);
    float xs_[8] = {va.x,va.y,va.z,va.w,vb.x,vb.y,vb.z,vb.w};
    #pragma unroll
    for(int j=0;j<8;j++){
      unsigned u = __float_as_uint(xs_[j]);
      unsigned short hb = (unsigned short)(u >> 16);
      ah[k0][j] = (short)hb;
      float ev = xs_[j] - __uint_as_float(((unsigned)hb) << 16);
      ae[k0][j] = (short)(unsigned short)(__float_as_uint(ev) >> 16);
    }
  }

  #pragma unroll 2
  for(int ct=0;ct<8;ct++){
    f4v a = (f4v){0.f,0.f,0.f,0.f};
    #pragma unroll
    for(int k0=0;k0<4;k0++){
      size_t boff = ((size_t)(ct*4 + k0)*64 + lane)*8;
      s8v bh = *(const s8v*)(pWh + boff);
      s8v be = *(const s8v*)(pWe + boff);
      a = __builtin_amdgcn_mfma_f32_16x16x32_bf16(ah[k0], bh, a, 0,0,0);
      a = __builtin_amdgcn_mfma_f32_16x16x32_bf16(ah[k0], be, a, 0,0,0);
      a = __builtin_amdgcn_mfma_f32_16x16x32_bf16(ae[k0], bh, a, 0,0,0);
    }
    float* dst = (ct < 4) ? xl : xr;
    int cc = (ct & 3)*16 + r;
    #pragma unroll
    for(int rr=0;rr<4;rr++){
      int row = rowbase + g*4 + rr;
      if(row < N){
        dst[(size_t)row*H + cc] = a[rr];
        if(ct < 4){
          unsigned u = __float_as_uint(a[rr]);
          xlb[(size_t)row*H + cc] = (unsigned short)((u + 0x7FFF + ((u>>16)&1)) >> 16); // RNE
        }
      }
    }
  }
}

// K2: per-block scan of deg, LOCAL-exclusive into rowptr + block totals.
__global__ __launch_bounds__(256) void k_scan_a(const int* __restrict__ deg, int n,
                                                int* __restrict__ rowptr,
                                                int* __restrict__ blocksum){
  __shared__ int wsum[4];
  int tid = threadIdx.x, lane = tid & 63, wid = tid >> 6;
  int idx = blockIdx.x*SCAN_CHUNK + tid*8;
  int v[8];
  if(idx + 8 <= n){
    int4 a = *(const int4*)(deg + idx);
    int4 b = *(const int4*)(deg + idx + 4);
    v[0]=a.x;v[1]=a.y;v[2]=a.z;v[3]=a.w;v[4]=b.x;v[5]=b.y;v[6]=b.z;v[7]=b.w;
  } else {
    #pragma unroll
    for(int i=0;i<8;i++) v[i] = (idx+i<n)? deg[idx+i] : 0;
  }
  int pre[8]; int st=0;
  #pragma unroll
  for(int i=0;i<8;i++){ pre[i]=st; st+=v[i]; }
  int incl = st;
  #pragma unroll
  for(int o=1;o<64;o<<=1){ int u=__shfl_up(incl,o); if(lane>=o) incl+=u; }
  if(lane==63) wsum[wid]=incl;
  __syncthreads();
  if(tid==0){ int accu=0; for(int i=0;i<4;i++){ int t=wsum[i]; wsum[i]=accu; accu+=t; } }
  __syncthreads();
  int toff = wsum[wid] + incl - st;
  if(idx + 8 <= n){
    int4 o0 = make_int4(toff+pre[0],toff+pre[1],toff+pre[2],toff+pre[3]);
    int4 o1 = make_int4(toff+pre[4],toff+pre[5],toff+pre[6],toff+pre[7]);
    *(int4*)(rowptr+idx)=o0; *(int4*)(rowptr+idx+4)=o1;
  } else {
    #pragma unroll
    for(int i=0;i<8;i++) if(idx+i<n) rowptr[idx+i]=toff+pre[i];
  }
  if(tid==255){
    blocksum[blockIdx.x] = toff + st;
    if(blockIdx.x == gridDim.x-1) rowptr[n] = toff + st;
  }
}

// K3: CSR fill — no atomics; 8 edges/thread; p = rowptr_local[dst] + bs[dst>>11] + rank[i]
__global__ void k_fill(const int* __restrict__ ei, int E, int Etot,
                       const int* __restrict__ rowptr,
                       const int* __restrict__ blocksum, int nscan,
                       const int* __restrict__ rank, int* __restrict__ csr_src){
  __shared__ int bs[64];
  int tid = threadIdx.x;
  load_bs(blocksum, nscan, bs, tid);
  int i0 = (blockIdx.x*blockDim.x + tid)*8;
  if(i0 >= Etot) return;
  if(i0 + 8 <= E && (E & 3) == 0){
    int4 sa = *(const int4*)(ei + i0);
    int4 sb = *(const int4*)(ei + i0 + 4);
    int4 da = *(const int4*)(ei + E + i0);
    int4 db = *(const int4*)(ei + E + i0 + 4);
    int4 ra = *(const int4*)(rank + i0);
    int4 rb = *(const int4*)(rank + i0 + 4);
    csr_src[rowptr[da.x] + bs[da.x>>11] + ra.x] = sa.x;
    csr_src[rowptr[da.y] + bs[da.y>>11] + ra.y] = sa.y;
    csr_src[rowptr[da.z] + bs[da.z>>11] + ra.z] = sa.z;
    csr_src[rowptr[da.w] + bs[da.w>>11] + ra.w] = sa.w;
    csr_src[rowptr[db.x] + bs[db.x>>11] + rb.x] = sb.x;
    csr_src[rowptr[db.y] + bs[db.y>>11] + rb.y] = sb.y;
    csr_src[rowptr[db.z] + bs[db.z>>11] + rb.z] = sb.z;
    csr_src[rowptr[db.w] + bs[db.w>>11] + rb.w] = sb.w;
  } else if(i0 >= E && i0 + 8 <= Etot){
    int4 ra = *(const int4*)(rank + i0);
    int4 rb = *(const int4*)(rank + i0 + 4);
    int v = i0 - E;
    csr_src[rowptr[v+0] + bs[(v+0)>>11] + ra.x] = v+0;
    csr_src[rowptr[v+1] + bs[(v+1)>>11] + ra.y] = v+1;
    csr_src[rowptr[v+2] + bs[(v+2)>>11] + ra.z] = v+2;
    csr_src[rowptr[v+3] + bs[(v+3)>>11] + ra.w] = v+3;
    csr_src[rowptr[v+4] + bs[(v+4)>>11] + rb.x] = v+4;
    csr_src[rowptr[v+5] + bs[(v+5)>>11] + rb.y] = v+5;
    csr_src[rowptr[v+6] + bs[(v+6)>>11] + rb.z] = v+6;
    csr_src[rowptr[v+7] + bs[(v+7)>>11] + rb.w] = v+7;
  } else {
    #pragma unroll
    for(int q=0;q<8;q++){
      int i = i0+q; if(i>=Etot) break;
      int src, dst;
      if(i<E){ src = ei[i]; dst = ei[E+i]; } else { src = i-E; dst = i-E; }
      csr_src[rowptr[dst] + bs[dst>>11] + rank[i]] = src;
    }
  }
}

// K4: fused layer-1 (no-max softmax).  32 lanes/node = 2 groups of 16, each group
// takes interleaved 8-edge chunks -> serial chunk depth halved; partials merged
// via shfl_xor(·,16); projections: group0 -> Wl2 cols, group1 -> Wr2 cols.
__global__ void k_node1f(const int* __restrict__ rowptr, const int* __restrict__ blocksum,
                         int nscan, const int* __restrict__ csr_src,
                         const unsigned short* __restrict__ xlb, const float* __restrict__ xr,
                         const float* __restrict__ att, const float* __restrict__ b1,
                         const float* __restrict__ Wl2, const float* __restrict__ Wr2,
                         float* __restrict__ xl2, float* __restrict__ xr2, int N){
  __shared__ int bs[64];
  int tid = threadIdx.x;
  load_bs(blocksum, nscan, bs, tid);
  int node = blockIdx.x*8 + (tid>>5);      // 8 nodes/block
  int half = (tid >> 4) & 1;               // which 16-lane group within the node
  int gl = tid & 15;
  if(node >= N) return;
  int f4 = gl*4;
  float4 attv = *(const float4*)(att + f4);
  float4 xrv  = *(const float4*)(xr + (size_t)node*H + f4);
  int s = rowptr[node]   + bs[node>>11];
  int t = rowptr[node+1] + bs[(node+1)>>11];
  float d = 0.f;
  float ax=0.f, ay=0.f, az=0.f, aw=0.f;

  for(int k = s + half*8; k < t; k += 16){
    int tl = t - 1;
    int ks[8]; float4 xv[8]; float msk[8];
    #pragma unroll
    for(int j=0;j<8;j++){
      int kj = k + j;
      ks[j] = (kj < t) ? kj : tl;
      msk[j] = (kj < t) ? 1.f : 0.f;
    }
    int ss[8];
    #pragma unroll
    for(int j=0;j<8;j++) ss[j] = csr_src[ks[j]];
    #pragma unroll
    for(int j=0;j<8;j++){
      ushort4 uv = *(const ushort4*)(xlb + (size_t)ss[j]*H + f4);
      xv[j].x = __uint_as_float((unsigned)uv.x << 16);
      xv[j].y = __uint_as_float((unsigned)uv.y << 16);
      xv[j].z = __uint_as_float((unsigned)uv.z << 16);
      xv[j].w = __uint_as_float((unsigned)uv.w << 16);
    }
    #pragma unroll
    for(int j=0;j<8;j++){
      float h0 = xv[j].x + xrv.x, h1 = xv[j].y + xrv.y;
      float h2 = xv[j].z + xrv.z, h3 = xv[j].w + xrv.w;
      float l0 = (h0>0.f)? h0 : NEG_SLOPE*h0;
      float l1 = (h1>0.f)? h1 : NEG_SLOPE*h1;
      float l2 = (h2>0.f)? h2 : NEG_SLOPE*h2;
      float l3 = (h3>0.f)? h3 : NEG_SLOPE*h3;
      float e = l0*attv.x + l1*attv.y + l2*attv.z + l3*attv.w;
      #pragma unroll
      for(int o=1;o<16;o<<=1) e += __shfl_xor(e,o);   // o=1,2,4,8: stays in group
      float w = msk[j] * __expf(e);
      d  += w;
      ax += w*xv[j].x; ay += w*xv[j].y; az += w*xv[j].z; aw += w*xv[j].w;
    }
  }

  // merge the two 16-lane groups (lane ^ 16 stays within the node's 32 lanes)
  d  += __shfl_xor(d,16);
  ax += __shfl_xor(ax,16); ay += __shfl_xor(ay,16);
  az += __shfl_xor(az,16); aw += __shfl_xor(aw,16);

  float inv = 1.f/(d + EPS);
  float4 bv = *(const float4*)(b1 + f4);
  float h0 = ax*inv + bv.x, h1 = ay*inv + bv.y;
  float h2 = az*inv + bv.z, h3 = aw*inv + bv.w;
  // group 'half' computes its projection pair: half=0 -> Wl2, half=1 -> Wr2
  const float* Wp = half ? Wr2 : Wl2;
  float pa = h0*Wp[(f4+0)*FOUT+0] + h1*Wp[(f4+1)*FOUT+0] + h2*Wp[(f4+2)*FOUT+0] + h3*Wp[(f4+3)*FOUT+0];
  float pb = h0*Wp[(f4+0)*FOUT+1] + h1*Wp[(f4+1)*FOUT+1] + h2*Wp[(f4+2)*FOUT+1] + h3*Wp[(f4+3)*FOUT+1];
  #pragma unroll
  for(int o=1;o<16;o<<=1){
    pa += __shfl_xor(pa,o); pb += __shfl_xor(pb,o);
  }
  if(gl==0){
    float2 pv = make_float2(pa,pb);
    if(half==0) *(float2*)(xl2 + node*2) = pv;
    else        *(float2*)(xr2 + node*2) = pv;
  }
}

// K5: layer-2 full conv, single pass (no-max), 16-lane group per node, 4 nodes/wave
__global__ void k_node2(const int* __restrict__ rowptr, const int* __restrict__ blocksum,
                        int nscan, const int* __restrict__ csr_src,
                        const float* __restrict__ xl2, const float* __restrict__ xr2,
                        const float* __restrict__ att2, const float* __restrict__ b2,
                        float* __restrict__ out, int N){
  __shared__ int bs[64];
  int tid = threadIdx.x;
  load_bs(blocksum, nscan, bs, tid);
  int node = blockIdx.x*16 + (tid>>4);
  int gl = tid & 15;
  if(node >= N) return;
  int s = rowptr[node]   + bs[node>>11];
  int t = rowptr[node+1] + bs[(node+1)>>11];
  float2 xrv = *(const float2*)(xr2 + node*2);
  float a0 = att2[0], a1 = att2[1];
  float den=0.f, n0=0.f, n1=0.f;
  for(int k=s+gl; k<t; k+=16){
    int src = csr_src[k];
    float2 xs = *(const float2*)(xl2 + src*2);
    float h0 = xs.x + xrv.x, h1 = xs.y + xrv.y;
    float l0 = (h0>0.f)? h0 : NEG_SLOPE*h0;
    float l1 = (h1>0.f)? h1 : NEG_SLOPE*h1;
    float ex = __expf(l0*a0 + l1*a1);
    den += ex; n0 += ex*xs.x; n1 += ex*xs.y;
  }
  #pragma unroll
  for(int o=1;o<16;o<<=1){
    den += __shfl_xor(den,o);
    n0  += __shfl_xor(n0,o);
    n1  += __shfl_xor(n1,o);
  }
  if(gl==0){
    float inv = 1.f/(den + EPS);
    out[node*2+0] = n0*inv + b2[0];
    out[node*2+1] = n1*inv + b2[1];
  }
}

extern "C" void kernel_launch(void* const* d_in, const int* in_sizes, int n_in,
                              void* d_out, int out_size, void* d_ws, size_t ws_size,
                              hipStream_t stream){
  const float* x    = (const float*)d_in[0];
  const int*   ei   = (const int*)d_in[1];
  const float* Wl1  = (const float*)d_in[2];
  const float* Wr1  = (const float*)d_in[3];
  const float* att1 = (const float*)d_in[4];
  const float* b1   = (const float*)d_in[5];
  const float* Wl2  = (const float*)d_in[6];
  const float* Wr2  = (const float*)d_in[7];
  const float* att2 = (const float*)d_in[8];
  const float* b2   = (const float*)d_in[9];
  int N = in_sizes[0]/FIN;
  int E = in_sizes[1]/2;
  int Etot = E + N;
  int nscan = (N + SCAN_CHUNK - 1) / SCAN_CHUNK;   // 25 for N=50000 (<=64 required)
  int noct  = (Etot + 7) / 8;                       // 8-edge packages
  int ZB = (N + 255) / 256;
  int GG = (N + 63) / 64;                           // gemm blocks
  int GDO = (noct + 255) / 256;                     // degree blocks

  char* w = (char*)d_ws;
  size_t off = 0;
  auto alloc = [&](size_t bytes)->void*{
    void* p = w + off;
    off = (off + bytes + 255) & ~(size_t)255;
    return p;
  };
  float* xl1     = (float*)alloc((size_t)N*H*4);
  float* xr1     = (float*)alloc((size_t)N*H*4);
  unsigned short* xlb = (unsigned short*)alloc((size_t)N*H*2);
  int*   csr_src = (int*)  alloc((size_t)Etot*4);
  int*   rank    = (int*)  alloc((size_t)Etot*4);
  int*   deg     = (int*)  alloc((size_t)N*4);
  int*   rowptr  = (int*)  alloc((size_t)(N+1)*4);
  int*   blocksum= (int*)  alloc((size_t)64*4);
  float* xl2     = (float*)alloc((size_t)N*2*4);
  float* xr2     = (float*)alloc((size_t)N*2*4);
  unsigned short* pWh = (unsigned short*)alloc((size_t)2048*8*2);
  unsigned short* pWe = (unsigned short*)alloc((size_t)2048*8*2);

  k_prep<<<ZB+8, 256, 0, stream>>>(deg, N, ZB, Wl1, Wr1, pWh, pWe);
  k_gemm_deg<<<GG+GDO, 256, 0, stream>>>(x, pWh, pWe, xl1, xr1, xlb, N, GG,
                                         ei, E, Etot, deg, rank);
  k_scan_a<<<nscan,256,0,stream>>>(deg, N, rowptr, blocksum);
  k_fill<<<GDO,256,0,stream>>>(ei, E, Etot, rowptr, blocksum, nscan, rank, csr_src);
  k_node1f<<<(N+7)/8, 256, 0, stream>>>(rowptr, blocksum, nscan, csr_src,
                                        xlb, xr1, att1, b1, Wl2, Wr2, xl2, xr2, N);
  k_node2<<<(N+15)/16, 256, 0, stream>>>(rowptr, blocksum, nscan, csr_src,
                                         xl2, xr2, att2, b2, (float*)d_out, N);
}